// Round 9
// baseline (559.117 us; speedup 1.0000x reference)
//
#include <hip/hip_runtime.h>
#include <math.h>

#define BATCH   131072
#define IN_F    80
#define EMB     64
#define NE      16
#define RANK    8
#define UDIM    16
#define NCLS    10
#define NUSERS  1000

// ---- workspace layout (bytes) ----
#define OFF_H      0ull                 // BATCH*64 f32 (h1, then h in-place)
#define OFF_A      33554432ull          // NUSERS*16*64 f32
#define OFF_TOPE   37650432ull
#define OFF_TOPW   38699008ull
#define OFF_PAIRB  39747584ull
#define OFF_PAIRW  40796160ull
#define OFF_HIST   41844736ull
#define OFF_OFFS   41845760ull
#define OFF_CUR    41846784ull

__device__ __forceinline__ float gelu_f(float v) {
    return 0.5f * v * (1.0f + erff(v * 0.70710678118654752440f));
}
__device__ __forceinline__ float4 gelu4(float4 v) {
    v.x = gelu_f(v.x); v.y = gelu_f(v.y); v.z = gelu_f(v.z); v.w = gelu_f(v.w);
    return v;
}
__device__ __forceinline__ float4 sfma4(float s, float4 w, float4 a) {
    a.x = fmaf(s, w.x, a.x); a.y = fmaf(s, w.y, a.y);
    a.z = fmaf(s, w.z, a.z); a.w = fmaf(s, w.w, a.w);
    return a;
}
__device__ __forceinline__ float4 ffma4(float4 v, float4 w, float4 a) {
    a.x = fmaf(v.x, w.x, a.x); a.y = fmaf(v.y, w.y, a.y);
    a.z = fmaf(v.z, w.z, a.z); a.w = fmaf(v.w, w.w, a.w);
    return a;
}
__device__ __forceinline__ float4 add4(float4 a, float4 b) {
    a.x += b.x; a.y += b.y; a.z += b.z; a.w += b.w; return a;
}
__device__ __forceinline__ float4 ln4(float4 z, float mu, float inv, float4 g, float4 bb) {
    float4 r;
    r.x = fmaf((z.x - mu) * inv, g.x, bb.x);
    r.y = fmaf((z.y - mu) * inv, g.y, bb.y);
    r.z = fmaf((z.z - mu) * inv, g.z, bb.z);
    r.w = fmaf((z.w - mu) * inv, g.w, bb.w);
    return r;
}

#define FMA16Z(S, WB) do { \
    z0 = sfma4((S), (WB)[0],  z0); z1 = sfma4((S), (WB)[1],  z1); \
    z2 = sfma4((S), (WB)[2],  z2); z3 = sfma4((S), (WB)[3],  z3); \
    z4 = sfma4((S), (WB)[4],  z4); z5 = sfma4((S), (WB)[5],  z5); \
    z6 = sfma4((S), (WB)[6],  z6); z7 = sfma4((S), (WB)[7],  z7); \
    z8 = sfma4((S), (WB)[8],  z8); z9 = sfma4((S), (WB)[9],  z9); \
    za = sfma4((S), (WB)[10], za); zb = sfma4((S), (WB)[11], zb); \
    zc = sfma4((S), (WB)[12], zc); zd = sfma4((S), (WB)[13], zd); \
    ze = sfma4((S), (WB)[14], ze); zf = sfma4((S), (WB)[15], zf); } while (0)

// ---------------- A[u][e][d] precompute ----------------
__global__ void k_prep(const float* __restrict__ gU, const float* __restrict__ gV,
                       const float* __restrict__ ut, float* __restrict__ A)
{
    int idx = blockIdx.x * 256 + threadIdx.x;
    if (idx >= NUSERS * NE) return;
    int u = idx / NE, e = idx - u * NE;

    const float4* up = (const float4*)(ut + (size_t)u * UDIM);
    float4 u0 = up[0], u1 = up[1], u2 = up[2], u3 = up[3];

    float4 va = make_float4(0.f, 0.f, 0.f, 0.f);
    float4 vb = make_float4(0.f, 0.f, 0.f, 0.f);
    const float4* gv4 = (const float4*)gV;
#define UVSTEP(UD, DD) do { \
        float4 g0 = gv4[(e * UDIM + (DD)) * 2 + 0]; \
        float4 g1 = gv4[(e * UDIM + (DD)) * 2 + 1]; \
        va = sfma4((UD), g0, va); vb = sfma4((UD), g1, vb); } while (0)
    UVSTEP(u0.x, 0);  UVSTEP(u0.y, 1);  UVSTEP(u0.z, 2);  UVSTEP(u0.w, 3);
    UVSTEP(u1.x, 4);  UVSTEP(u1.y, 5);  UVSTEP(u1.z, 6);  UVSTEP(u1.w, 7);
    UVSTEP(u2.x, 8);  UVSTEP(u2.y, 9);  UVSTEP(u2.z, 10); UVSTEP(u2.w, 11);
    UVSTEP(u3.x, 12); UVSTEP(u3.y, 13); UVSTEP(u3.z, 14); UVSTEP(u3.w, 15);
#undef UVSTEP

    const float4* gu4 = (const float4*)gU;
    float* Ao = A + ((size_t)u * NE + e) * EMB;
    for (int d = 0; d < EMB; ++d) {
        float4 q0 = gu4[(e * EMB + d) * 2 + 0];
        float4 q1 = gu4[(e * EMB + d) * 2 + 1];
        float a = 0.0f;
        a = fmaf(q0.x, va.x, a); a = fmaf(q0.y, va.y, a);
        a = fmaf(q0.z, va.z, a); a = fmaf(q0.w, va.w, a);
        a = fmaf(q1.x, vb.x, a); a = fmaf(q1.y, vb.y, a);
        a = fmaf(q1.z, vb.z, a); a = fmaf(q1.w, vb.w, a);
        Ao[d] = a;
    }
}

// ---------------- fc1: x streamed once, z(64) acc, gelu -> h1 ----------------
// live ~80 floats; cap 168 (min-waves 3) is safe -> 12 waves/CU
__global__ __launch_bounds__(256, 3) void k_fc1(
    const float* __restrict__ x,
    const float* __restrict__ w1, const float* __restrict__ b1,
    float* __restrict__ h1_out)
{
    __shared__ __align__(16) float4 s_w1[IN_F * 16];   // 20 KB [d][k4]
    __shared__ __align__(16) float4 s_b1[16];

    const int tid = threadIdx.x;
    {
        const float4* g1 = (const float4*)w1;
        for (int i = tid; i < IN_F * 16; i += 256) s_w1[i] = g1[i];
        if (tid < 16) s_b1[tid] = ((const float4*)b1)[tid];
    }
    __syncthreads();

    const int b = blockIdx.x * 256 + tid;
    const float4* xp = (const float4*)(x + (size_t)b * IN_F);

    float4 z0 = s_b1[0],  z1 = s_b1[1],  z2 = s_b1[2],  z3 = s_b1[3];
    float4 z4 = s_b1[4],  z5 = s_b1[5],  z6 = s_b1[6],  z7 = s_b1[7];
    float4 z8 = s_b1[8],  z9 = s_b1[9],  za = s_b1[10], zb = s_b1[11];
    float4 zc = s_b1[12], zd = s_b1[13], ze = s_b1[14], zf = s_b1[15];

#pragma unroll 1
    for (int t = 0; t < 5; ++t) {
        float4 xA = xp[4*t+0], xB = xp[4*t+1], xC = xp[4*t+2], xD = xp[4*t+3];
        const float4* wr = s_w1 + (t * 16) * 16;
        FMA16Z(xA.x, wr);       FMA16Z(xA.y, wr + 16);  FMA16Z(xA.z, wr + 32);  FMA16Z(xA.w, wr + 48);
        FMA16Z(xB.x, wr + 64);  FMA16Z(xB.y, wr + 80);  FMA16Z(xB.z, wr + 96);  FMA16Z(xB.w, wr + 112);
        FMA16Z(xC.x, wr + 128); FMA16Z(xC.y, wr + 144); FMA16Z(xC.z, wr + 160); FMA16Z(xC.w, wr + 176);
        FMA16Z(xD.x, wr + 192); FMA16Z(xD.y, wr + 208); FMA16Z(xD.z, wr + 224); FMA16Z(xD.w, wr + 240);
    }
    z0 = gelu4(z0); z1 = gelu4(z1); z2 = gelu4(z2); z3 = gelu4(z3);
    z4 = gelu4(z4); z5 = gelu4(z5); z6 = gelu4(z6); z7 = gelu4(z7);
    z8 = gelu4(z8); z9 = gelu4(z9); za = gelu4(za); zb = gelu4(zb);
    zc = gelu4(zc); zd = gelu4(zd); ze = gelu4(ze); zf = gelu4(zf);

    float4* ho = (float4*)(h1_out + (size_t)b * EMB);
    ho[0] = z0;  ho[1] = z1;  ho[2] = z2;  ho[3] = z3;
    ho[4] = z4;  ho[5] = z5;  ho[6] = z6;  ho[7] = z7;
    ho[8] = z8;  ho[9] = z9;  ho[10] = za; ho[11] = zb;
    ho[12] = zc; ho[13] = zd; ho[14] = ze; ho[15] = zf;
}

// ---------------- fc2 + gelu + LN + gate + top2; h1 -> h in place ----------------
__global__ __launch_bounds__(256, 3) void k_fc2gate(
    float* h,                                 // in: h1, out: h (same buffer, own row)
    const int* __restrict__ uid,
    const float* __restrict__ w2, const float* __restrict__ b2,
    const float* __restrict__ gam, const float* __restrict__ bet,
    const float* __restrict__ A, const float* __restrict__ gb,
    int* __restrict__ top_e, float* __restrict__ top_w, int* __restrict__ hist)
{
    __shared__ __align__(16) float4 s_w2[EMB * 16];    // 16 KB [d][k4]
    __shared__ __align__(16) float4 s_b2[16], s_ga[16], s_be[16];
    __shared__ float s_gb[NE];
    __shared__ int s_hist[NE];

    const int tid = threadIdx.x;
    {
        const float4* g2 = (const float4*)w2;
        for (int i = tid; i < EMB * 16; i += 256) s_w2[i] = g2[i];
        if (tid < 16) {
            s_b2[tid] = ((const float4*)b2)[tid];
            s_ga[tid] = ((const float4*)gam)[tid];
            s_be[tid] = ((const float4*)bet)[tid];
        }
        if (tid < NE) { s_gb[tid] = gb[tid]; s_hist[tid] = 0; }
    }
    __syncthreads();

    const int b = blockIdx.x * 256 + tid;
    float4* hp = (float4*)(h + (size_t)b * EMB);

    float4 z0 = s_b2[0],  z1 = s_b2[1],  z2 = s_b2[2],  z3 = s_b2[3];
    float4 z4 = s_b2[4],  z5 = s_b2[5],  z6 = s_b2[6],  z7 = s_b2[7];
    float4 z8 = s_b2[8],  z9 = s_b2[9],  za = s_b2[10], zb = s_b2[11];
    float4 zc = s_b2[12], zd = s_b2[13], ze = s_b2[14], zf = s_b2[15];
#pragma unroll 1
    for (int t = 0; t < 4; ++t) {
        float4 hA = hp[4*t+0], hB = hp[4*t+1], hC = hp[4*t+2], hD = hp[4*t+3];
        const float4* wr = s_w2 + (t * 16) * 16;
        FMA16Z(hA.x, wr);       FMA16Z(hA.y, wr + 16);  FMA16Z(hA.z, wr + 32);  FMA16Z(hA.w, wr + 48);
        FMA16Z(hB.x, wr + 64);  FMA16Z(hB.y, wr + 80);  FMA16Z(hB.z, wr + 96);  FMA16Z(hB.w, wr + 112);
        FMA16Z(hC.x, wr + 128); FMA16Z(hC.y, wr + 144); FMA16Z(hC.z, wr + 160); FMA16Z(hC.w, wr + 176);
        FMA16Z(hD.x, wr + 192); FMA16Z(hD.y, wr + 208); FMA16Z(hD.z, wr + 224); FMA16Z(hD.w, wr + 240);
    }
    z0 = gelu4(z0); z1 = gelu4(z1); z2 = gelu4(z2); z3 = gelu4(z3);
    z4 = gelu4(z4); z5 = gelu4(z5); z6 = gelu4(z6); z7 = gelu4(z7);
    z8 = gelu4(z8); z9 = gelu4(z9); za = gelu4(za); zb = gelu4(zb);
    zc = gelu4(zc); zd = gelu4(zd); ze = gelu4(ze); zf = gelu4(zf);

    // LayerNorm
    float4 sA = add4(add4(add4(z0, z1), add4(z2, z3)), add4(add4(z4, z5), add4(z6, z7)));
    float4 sB = add4(add4(add4(z8, z9), add4(za, zb)), add4(add4(zc, zd), add4(ze, zf)));
    float4 sS = add4(sA, sB);
    float mu = (sS.x + sS.y + sS.z + sS.w) * (1.0f / 64.0f);
    float4 vv = make_float4(0.f, 0.f, 0.f, 0.f);
#define BBV(Z) do { float4 d4; d4.x = (Z).x - mu; d4.y = (Z).y - mu; d4.z = (Z).z - mu; d4.w = (Z).w - mu; \
                    vv = ffma4(d4, d4, vv); } while (0)
    BBV(z0); BBV(z1); BBV(z2); BBV(z3); BBV(z4); BBV(z5); BBV(z6); BBV(z7);
    BBV(z8); BBV(z9); BBV(za); BBV(zb); BBV(zc); BBV(zd); BBV(ze); BBV(zf);
#undef BBV
    float var = (vv.x + vv.y + vv.z + vv.w) * (1.0f / 64.0f);
    float inv = 1.0f / sqrtf(var + 1e-5f);
    z0 = ln4(z0, mu, inv, s_ga[0],  s_be[0]);
    z1 = ln4(z1, mu, inv, s_ga[1],  s_be[1]);
    z2 = ln4(z2, mu, inv, s_ga[2],  s_be[2]);
    z3 = ln4(z3, mu, inv, s_ga[3],  s_be[3]);
    z4 = ln4(z4, mu, inv, s_ga[4],  s_be[4]);
    z5 = ln4(z5, mu, inv, s_ga[5],  s_be[5]);
    z6 = ln4(z6, mu, inv, s_ga[6],  s_be[6]);
    z7 = ln4(z7, mu, inv, s_ga[7],  s_be[7]);
    z8 = ln4(z8, mu, inv, s_ga[8],  s_be[8]);
    z9 = ln4(z9, mu, inv, s_ga[9],  s_be[9]);
    za = ln4(za, mu, inv, s_ga[10], s_be[10]);
    zb = ln4(zb, mu, inv, s_ga[11], s_be[11]);
    zc = ln4(zc, mu, inv, s_ga[12], s_be[12]);
    zd = ln4(zd, mu, inv, s_ga[13], s_be[13]);
    ze = ln4(ze, mu, inv, s_ga[14], s_be[14]);
    zf = ln4(zf, mu, inv, s_ga[15], s_be[15]);

    hp[0] = z0;  hp[1] = z1;  hp[2] = z2;  hp[3] = z3;
    hp[4] = z4;  hp[5] = z5;  hp[6] = z6;  hp[7] = z7;
    hp[8] = z8;  hp[9] = z9;  hp[10] = za; hp[11] = zb;
    hp[12] = zc; hp[13] = zd; hp[14] = ze; hp[15] = zf;

    // gate + running top-2 (lowest index wins ties)
    const int u = uid[b];
    const float4* Ap = (const float4*)(A + (size_t)u * NE * EMB);
    float m0 = -1e30f, m1 = -1e30f;
    int i0 = 0, i1 = 0;
#pragma unroll 1
    for (int e = 0; e < NE; ++e) {
        const float4* ap = Ap + e * 16;
        float4 ac = make_float4(0.f, 0.f, 0.f, 0.f);
        ac = ffma4(z0, ap[0],  ac); ac = ffma4(z1, ap[1],  ac);
        ac = ffma4(z2, ap[2],  ac); ac = ffma4(z3, ap[3],  ac);
        ac = ffma4(z4, ap[4],  ac); ac = ffma4(z5, ap[5],  ac);
        ac = ffma4(z6, ap[6],  ac); ac = ffma4(z7, ap[7],  ac);
        ac = ffma4(z8, ap[8],  ac); ac = ffma4(z9, ap[9],  ac);
        ac = ffma4(za, ap[10], ac); ac = ffma4(zb, ap[11], ac);
        ac = ffma4(zc, ap[12], ac); ac = ffma4(zd, ap[13], ac);
        ac = ffma4(ze, ap[14], ac); ac = ffma4(zf, ap[15], ac);
        float ge = ((ac.x + ac.y) + (ac.z + ac.w)) + s_gb[e];
        if (ge > m0)      { m1 = m0; i1 = i0; m0 = ge; i0 = e; }
        else if (ge > m1) { m1 = ge; i1 = e; }
    }
    float t = expf(m1 - m0);
    float w0n = 1.0f / (1.0f + t);
    float w1n = t / (1.0f + t);

    top_e[2*b+0] = i0; top_w[2*b+0] = w0n;
    top_e[2*b+1] = i1; top_w[2*b+1] = w1n;
    atomicAdd(&s_hist[i0], 1);
    atomicAdd(&s_hist[i1], 1);
    __syncthreads();
    if (tid < NE) atomicAdd(&hist[tid], s_hist[tid]);
}

// ---------------- tiny exclusive scan ----------------
__global__ void k_scan(const int* __restrict__ hist, int* __restrict__ offs, int* __restrict__ cur)
{
    if (blockIdx.x == 0 && threadIdx.x == 0) {
        int acc = 0;
        for (int e = 0; e < NE; ++e) { offs[e] = acc; cur[e] = acc; acc += hist[e]; }
    }
}

// ---------------- block-aggregated scatter ----------------
__global__ __launch_bounds__(256) void k_scatter(
    const int* __restrict__ top_e, const float* __restrict__ top_w,
    int* __restrict__ cur, int* __restrict__ pair_b, float* __restrict__ pair_w)
{
    __shared__ int lh[NE];
    __shared__ int lbase[NE];
    const int tid = threadIdx.x;
    if (tid < NE) lh[tid] = 0;
    __syncthreads();

    const int b = blockIdx.x * 256 + tid;
    const int e0 = top_e[2*b+0];
    const int e1 = top_e[2*b+1];
    atomicAdd(&lh[e0], 1);
    atomicAdd(&lh[e1], 1);
    __syncthreads();
    if (tid < NE) {
        lbase[tid] = atomicAdd(&cur[tid], lh[tid]);
        lh[tid] = 0;
    }
    __syncthreads();
    int r0 = atomicAdd(&lh[e0], 1);
    int p0 = lbase[e0] + r0;
    pair_b[p0] = b; pair_w[p0] = top_w[2*b+0];
    int r1 = atomicAdd(&lh[e1], 1);
    int p1 = lbase[e1] + r1;
    pair_b[p1] = b; pair_w[p1] = top_w[2*b+1];
}

// ---------------- expert: z(64) in regs, h streamed; occupancy-tuned ----------------
// EXP_BX=48 -> 768 blocks (3/CU); min-waves 3 caps VGPR at ~168 >= live ~85.
#define EXP_BX 48
__global__ __launch_bounds__(256, 3) void k_expert(
    const float* __restrict__ h,
    const int* __restrict__ pair_b, const float* __restrict__ pair_w,
    const int* __restrict__ hist, const int* __restrict__ offs,
    const float* __restrict__ ew1, const float* __restrict__ eb1,
    const float* __restrict__ eg, const float* __restrict__ ebeta,
    const float* __restrict__ ew2, const float* __restrict__ eb2,
    float* __restrict__ out)
{
    const int e = blockIdx.y;
    const int cnt = hist[e];
    if ((int)(blockIdx.x * 256) >= cnt) return;

    __shared__ __align__(16) float4 s_w1[EMB * 16];    // 16 KB [d][k4]
    __shared__ __align__(16) float4 s_w2[EMB * 3];     // 3 KB  [k][c4] padded 10->12
    __shared__ __align__(16) float4 s_b1[16], s_ga[16], s_be[16], s_b2[3];

    const int tid = threadIdx.x;
    {
        const float4* g1 = (const float4*)(ew1 + (size_t)e * EMB * EMB);
        for (int i = tid; i < EMB * 16; i += 256) s_w1[i] = g1[i];
        float* w2f = (float*)s_w2;
        for (int i = tid; i < EMB * 12; i += 256) {
            int k = i / 12, c = i - k * 12;
            w2f[i] = (c < NCLS) ? ew2[((size_t)e * EMB + k) * NCLS + c] : 0.0f;
        }
        if (tid < 16) {
            s_b1[tid] = ((const float4*)(eb1   + (size_t)e * EMB))[tid];
            s_ga[tid] = ((const float4*)(eg    + (size_t)e * EMB))[tid];
            s_be[tid] = ((const float4*)(ebeta + (size_t)e * EMB))[tid];
        }
        float* b2f = (float*)s_b2;
        if (tid < 12) b2f[tid] = (tid < NCLS) ? eb2[e * NCLS + tid] : 0.0f;
    }
    __syncthreads();

    const int base = offs[e];

    for (int lane = blockIdx.x * 256 + tid; lane < cnt; lane += EXP_BX * 256) {
        const int idx = base + lane;
        const int b = pair_b[idx];
        const float pw = pair_w[idx];

        const float4* hp = (const float4*)(h + (size_t)b * EMB);

        float4 z0 = s_b1[0],  z1 = s_b1[1],  z2 = s_b1[2],  z3 = s_b1[3];
        float4 z4 = s_b1[4],  z5 = s_b1[5],  z6 = s_b1[6],  z7 = s_b1[7];
        float4 z8 = s_b1[8],  z9 = s_b1[9],  za = s_b1[10], zb = s_b1[11];
        float4 zc = s_b1[12], zd = s_b1[13], ze = s_b1[14], zf = s_b1[15];
#pragma unroll 1
        for (int t = 0; t < 4; ++t) {
            float4 hA = hp[4*t+0], hB = hp[4*t+1], hC = hp[4*t+2], hD = hp[4*t+3];
            const float4* wr = s_w1 + (t * 16) * 16;
            FMA16Z(hA.x, wr);       FMA16Z(hA.y, wr + 16);  FMA16Z(hA.z, wr + 32);  FMA16Z(hA.w, wr + 48);
            FMA16Z(hB.x, wr + 64);  FMA16Z(hB.y, wr + 80);  FMA16Z(hB.z, wr + 96);  FMA16Z(hB.w, wr + 112);
            FMA16Z(hC.x, wr + 128); FMA16Z(hC.y, wr + 144); FMA16Z(hC.z, wr + 160); FMA16Z(hC.w, wr + 176);
            FMA16Z(hD.x, wr + 192); FMA16Z(hD.y, wr + 208); FMA16Z(hD.z, wr + 224); FMA16Z(hD.w, wr + 240);
        }
        z0 = gelu4(z0); z1 = gelu4(z1); z2 = gelu4(z2); z3 = gelu4(z3);
        z4 = gelu4(z4); z5 = gelu4(z5); z6 = gelu4(z6); z7 = gelu4(z7);
        z8 = gelu4(z8); z9 = gelu4(z9); za = gelu4(za); zb = gelu4(zb);
        zc = gelu4(zc); zd = gelu4(zd); ze = gelu4(ze); zf = gelu4(zf);

        float4 sA = add4(add4(add4(z0, z1), add4(z2, z3)), add4(add4(z4, z5), add4(z6, z7)));
        float4 sB = add4(add4(add4(z8, z9), add4(za, zb)), add4(add4(zc, zd), add4(ze, zf)));
        float4 sS = add4(sA, sB);
        float mu = (sS.x + sS.y + sS.z + sS.w) * (1.0f / 64.0f);
        float4 vv = make_float4(0.f, 0.f, 0.f, 0.f);
#define EXV(Z) do { float4 d4; d4.x = (Z).x - mu; d4.y = (Z).y - mu; d4.z = (Z).z - mu; d4.w = (Z).w - mu; \
                    vv = ffma4(d4, d4, vv); } while (0)
        EXV(z0); EXV(z1); EXV(z2); EXV(z3); EXV(z4); EXV(z5); EXV(z6); EXV(z7);
        EXV(z8); EXV(z9); EXV(za); EXV(zb); EXV(zc); EXV(zd); EXV(ze); EXV(zf);
#undef EXV
        float var = (vv.x + vv.y + vv.z + vv.w) * (1.0f / 64.0f);
        float inv = 1.0f / sqrtf(var + 1e-5f);
        z0 = ln4(z0, mu, inv, s_ga[0],  s_be[0]);
        z1 = ln4(z1, mu, inv, s_ga[1],  s_be[1]);
        z2 = ln4(z2, mu, inv, s_ga[2],  s_be[2]);
        z3 = ln4(z3, mu, inv, s_ga[3],  s_be[3]);
        z4 = ln4(z4, mu, inv, s_ga[4],  s_be[4]);
        z5 = ln4(z5, mu, inv, s_ga[5],  s_be[5]);
        z6 = ln4(z6, mu, inv, s_ga[6],  s_be[6]);
        z7 = ln4(z7, mu, inv, s_ga[7],  s_be[7]);
        z8 = ln4(z8, mu, inv, s_ga[8],  s_be[8]);
        z9 = ln4(z9, mu, inv, s_ga[9],  s_be[9]);
        za = ln4(za, mu, inv, s_ga[10], s_be[10]);
        zb = ln4(zb, mu, inv, s_ga[11], s_be[11]);
        zc = ln4(zc, mu, inv, s_ga[12], s_be[12]);
        zd = ln4(zd, mu, inv, s_ga[13], s_be[13]);
        ze = ln4(ze, mu, inv, s_ga[14], s_be[14]);
        zf = ln4(zf, mu, inv, s_ga[15], s_be[15]);

        float4 a0 = s_b2[0], a1 = s_b2[1], a2 = s_b2[2];
#define EXF2(ZQ, DB) do { \
        const float4* wr = s_w2 + (DB) * 3; \
        a0 = sfma4((ZQ).x, wr[0],  a0); a1 = sfma4((ZQ).x, wr[1],  a1); a2 = sfma4((ZQ).x, wr[2],  a2); \
        a0 = sfma4((ZQ).y, wr[3],  a0); a1 = sfma4((ZQ).y, wr[4],  a1); a2 = sfma4((ZQ).y, wr[5],  a2); \
        a0 = sfma4((ZQ).z, wr[6],  a0); a1 = sfma4((ZQ).z, wr[7],  a1); a2 = sfma4((ZQ).z, wr[8],  a2); \
        a0 = sfma4((ZQ).w, wr[9],  a0); a1 = sfma4((ZQ).w, wr[10], a1); a2 = sfma4((ZQ).w, wr[11], a2); \
} while (0)
        EXF2(z0, 0);  EXF2(z1, 4);  EXF2(z2, 8);  EXF2(z3, 12);
        EXF2(z4, 16); EXF2(z5, 20); EXF2(z6, 24); EXF2(z7, 28);
        EXF2(z8, 32); EXF2(z9, 36); EXF2(za, 40); EXF2(zb, 44);
        EXF2(zc, 48); EXF2(zd, 52); EXF2(ze, 56); EXF2(zf, 60);
#undef EXF2

        float* ob = out + (size_t)b * NCLS;
        atomicAdd(ob + 0, pw * a0.x);
        atomicAdd(ob + 1, pw * a0.y);
        atomicAdd(ob + 2, pw * a0.z);
        atomicAdd(ob + 3, pw * a0.w);
        atomicAdd(ob + 4, pw * a1.x);
        atomicAdd(ob + 5, pw * a1.y);
        atomicAdd(ob + 6, pw * a1.z);
        atomicAdd(ob + 7, pw * a1.w);
        atomicAdd(ob + 8, pw * a2.x);
        atomicAdd(ob + 9, pw * a2.y);
    }
}

extern "C" void kernel_launch(void* const* d_in, const int* in_sizes, int n_in,
                              void* d_out, int out_size, void* d_ws, size_t ws_size,
                              hipStream_t stream)
{
    (void)in_sizes; (void)n_in; (void)out_size; (void)ws_size;

    const float* x     = (const float*)d_in[0];
    const int*   uid   = (const int*)  d_in[1];
    const float* bb_w1 = (const float*)d_in[2];
    const float* bb_b1 = (const float*)d_in[3];
    const float* bb_w2 = (const float*)d_in[4];
    const float* bb_b2 = (const float*)d_in[5];
    const float* bb_g  = (const float*)d_in[6];
    const float* bb_be = (const float*)d_in[7];
    const float* gU    = (const float*)d_in[8];
    const float* gV    = (const float*)d_in[9];
    const float* gb    = (const float*)d_in[10];
    const float* e_w1  = (const float*)d_in[11];
    const float* e_b1  = (const float*)d_in[12];
    const float* e_g   = (const float*)d_in[13];
    const float* e_be  = (const float*)d_in[14];
    const float* e_w2  = (const float*)d_in[15];
    const float* e_b2  = (const float*)d_in[16];
    const float* ut    = (const float*)d_in[17];

    float* out = (float*)d_out;
    char*  ws  = (char*)d_ws;

    float* h      = (float*)(ws + OFF_H);
    float* A      = (float*)(ws + OFF_A);
    int*   top_e  = (int*)  (ws + OFF_TOPE);
    float* top_w  = (float*)(ws + OFF_TOPW);
    int*   pair_b = (int*)  (ws + OFF_PAIRB);
    float* pair_w = (float*)(ws + OFF_PAIRW);
    int*   hist   = (int*)  (ws + OFF_HIST);
    int*   offs   = (int*)  (ws + OFF_OFFS);
    int*   cur    = (int*)  (ws + OFF_CUR);

    hipMemsetAsync(out, 0, (size_t)BATCH * NCLS * sizeof(float), stream);
    hipMemsetAsync(hist, 0, NE * sizeof(int), stream);

    k_prep<<<(NUSERS * NE + 255) / 256, 256, 0, stream>>>(gU, gV, ut, A);
    k_fc1<<<BATCH / 256, 256, 0, stream>>>(x, bb_w1, bb_b1, h);
    k_fc2gate<<<BATCH / 256, 256, 0, stream>>>(h, uid, bb_w2, bb_b2, bb_g, bb_be,
                                               A, gb, top_e, top_w, hist);
    k_scan<<<1, 64, 0, stream>>>(hist, offs, cur);
    k_scatter<<<BATCH / 256, 256, 0, stream>>>(top_e, top_w, cur, pair_b, pair_w);
    dim3 eg(EXP_BX, NE);
    k_expert<<<eg, 256, 0, stream>>>(h, pair_b, pair_w, hist, offs,
                                     e_w1, e_b1, e_g, e_be, e_w2, e_b2, out);
}

// Round 10
// 547.755 us; speedup vs baseline: 1.0207x; 1.0207x over previous
//
#include <hip/hip_runtime.h>
#include <math.h>

#define BATCH   131072
#define IN_F    80
#define EMB     64
#define NE      16
#define RANK    8
#define UDIM    16
#define NCLS    10
#define NUSERS  1000

// ---- workspace layout (bytes) ----
#define OFF_H      0ull                 // BATCH*64 f32 (h1, then h in-place)
#define OFF_A      33554432ull          // NUSERS*16*64 f32
#define OFF_TOPE   37650432ull
#define OFF_TOPW   38699008ull
#define OFF_PAIRB  39747584ull
#define OFF_PAIRW  40796160ull
#define OFF_HIST   41844736ull
#define OFF_OFFS   41845760ull
#define OFF_CUR    41846784ull

__device__ __forceinline__ float gelu_f(float v) {
    return 0.5f * v * (1.0f + erff(v * 0.70710678118654752440f));
}
__device__ __forceinline__ float4 gelu4(float4 v) {
    v.x = gelu_f(v.x); v.y = gelu_f(v.y); v.z = gelu_f(v.z); v.w = gelu_f(v.w);
    return v;
}
__device__ __forceinline__ float4 sfma4(float s, float4 w, float4 a) {
    a.x = fmaf(s, w.x, a.x); a.y = fmaf(s, w.y, a.y);
    a.z = fmaf(s, w.z, a.z); a.w = fmaf(s, w.w, a.w);
    return a;
}
__device__ __forceinline__ float4 ffma4(float4 v, float4 w, float4 a) {
    a.x = fmaf(v.x, w.x, a.x); a.y = fmaf(v.y, w.y, a.y);
    a.z = fmaf(v.z, w.z, a.z); a.w = fmaf(v.w, w.w, a.w);
    return a;
}
__device__ __forceinline__ float4 add4(float4 a, float4 b) {
    a.x += b.x; a.y += b.y; a.z += b.z; a.w += b.w; return a;
}
__device__ __forceinline__ float4 ln4(float4 z, float mu, float inv, float4 g, float4 bb) {
    float4 r;
    r.x = fmaf((z.x - mu) * inv, g.x, bb.x);
    r.y = fmaf((z.y - mu) * inv, g.y, bb.y);
    r.z = fmaf((z.z - mu) * inv, g.z, bb.z);
    r.w = fmaf((z.w - mu) * inv, g.w, bb.w);
    return r;
}

#define FMA16Z(S, WB) do { \
    z0 = sfma4((S), (WB)[0],  z0); z1 = sfma4((S), (WB)[1],  z1); \
    z2 = sfma4((S), (WB)[2],  z2); z3 = sfma4((S), (WB)[3],  z3); \
    z4 = sfma4((S), (WB)[4],  z4); z5 = sfma4((S), (WB)[5],  z5); \
    z6 = sfma4((S), (WB)[6],  z6); z7 = sfma4((S), (WB)[7],  z7); \
    z8 = sfma4((S), (WB)[8],  z8); z9 = sfma4((S), (WB)[9],  z9); \
    za = sfma4((S), (WB)[10], za); zb = sfma4((S), (WB)[11], zb); \
    zc = sfma4((S), (WB)[12], zc); zd = sfma4((S), (WB)[13], zd); \
    ze = sfma4((S), (WB)[14], ze); zf = sfma4((S), (WB)[15], zf); } while (0)

// ---------------- A[u][e][d] precompute ----------------
__global__ void k_prep(const float* __restrict__ gU, const float* __restrict__ gV,
                       const float* __restrict__ ut, float* __restrict__ A)
{
    int idx = blockIdx.x * 256 + threadIdx.x;
    if (idx >= NUSERS * NE) return;
    int u = idx / NE, e = idx - u * NE;

    const float4* up = (const float4*)(ut + (size_t)u * UDIM);
    float4 u0 = up[0], u1 = up[1], u2 = up[2], u3 = up[3];

    float4 va = make_float4(0.f, 0.f, 0.f, 0.f);
    float4 vb = make_float4(0.f, 0.f, 0.f, 0.f);
    const float4* gv4 = (const float4*)gV;
#define UVSTEP(UD, DD) do { \
        float4 g0 = gv4[(e * UDIM + (DD)) * 2 + 0]; \
        float4 g1 = gv4[(e * UDIM + (DD)) * 2 + 1]; \
        va = sfma4((UD), g0, va); vb = sfma4((UD), g1, vb); } while (0)
    UVSTEP(u0.x, 0);  UVSTEP(u0.y, 1);  UVSTEP(u0.z, 2);  UVSTEP(u0.w, 3);
    UVSTEP(u1.x, 4);  UVSTEP(u1.y, 5);  UVSTEP(u1.z, 6);  UVSTEP(u1.w, 7);
    UVSTEP(u2.x, 8);  UVSTEP(u2.y, 9);  UVSTEP(u2.z, 10); UVSTEP(u2.w, 11);
    UVSTEP(u3.x, 12); UVSTEP(u3.y, 13); UVSTEP(u3.z, 14); UVSTEP(u3.w, 15);
#undef UVSTEP

    const float4* gu4 = (const float4*)gU;
    float* Ao = A + ((size_t)u * NE + e) * EMB;
    for (int d = 0; d < EMB; ++d) {
        float4 q0 = gu4[(e * EMB + d) * 2 + 0];
        float4 q1 = gu4[(e * EMB + d) * 2 + 1];
        float a = 0.0f;
        a = fmaf(q0.x, va.x, a); a = fmaf(q0.y, va.y, a);
        a = fmaf(q0.z, va.z, a); a = fmaf(q0.w, va.w, a);
        a = fmaf(q1.x, vb.x, a); a = fmaf(q1.y, vb.y, a);
        a = fmaf(q1.z, vb.z, a); a = fmaf(q1.w, vb.w, a);
        Ao[d] = a;
    }
}

// ---------------- fc1: x streamed once, z(64) acc, gelu -> h1 ----------------
// live ~100 < cap 128 (min-waves 2 => allocator cap 256/2) -> 16 waves/CU
__global__ __launch_bounds__(256, 2) void k_fc1(
    const float* __restrict__ x,
    const float* __restrict__ w1, const float* __restrict__ b1,
    float* __restrict__ h1_out)
{
    __shared__ __align__(16) float4 s_w1[IN_F * 16];   // 20 KB [d][k4]
    __shared__ __align__(16) float4 s_b1[16];

    const int tid = threadIdx.x;
    {
        const float4* g1 = (const float4*)w1;
        for (int i = tid; i < IN_F * 16; i += 256) s_w1[i] = g1[i];
        if (tid < 16) s_b1[tid] = ((const float4*)b1)[tid];
    }
    __syncthreads();

    const int b = blockIdx.x * 256 + tid;
    const float4* xp = (const float4*)(x + (size_t)b * IN_F);

    float4 z0 = s_b1[0],  z1 = s_b1[1],  z2 = s_b1[2],  z3 = s_b1[3];
    float4 z4 = s_b1[4],  z5 = s_b1[5],  z6 = s_b1[6],  z7 = s_b1[7];
    float4 z8 = s_b1[8],  z9 = s_b1[9],  za = s_b1[10], zb = s_b1[11];
    float4 zc = s_b1[12], zd = s_b1[13], ze = s_b1[14], zf = s_b1[15];

#pragma unroll 1
    for (int t = 0; t < 5; ++t) {
        float4 xA = xp[4*t+0], xB = xp[4*t+1], xC = xp[4*t+2], xD = xp[4*t+3];
        const float4* wr = s_w1 + (t * 16) * 16;
        FMA16Z(xA.x, wr);       FMA16Z(xA.y, wr + 16);  FMA16Z(xA.z, wr + 32);  FMA16Z(xA.w, wr + 48);
        FMA16Z(xB.x, wr + 64);  FMA16Z(xB.y, wr + 80);  FMA16Z(xB.z, wr + 96);  FMA16Z(xB.w, wr + 112);
        FMA16Z(xC.x, wr + 128); FMA16Z(xC.y, wr + 144); FMA16Z(xC.z, wr + 160); FMA16Z(xC.w, wr + 176);
        FMA16Z(xD.x, wr + 192); FMA16Z(xD.y, wr + 208); FMA16Z(xD.z, wr + 224); FMA16Z(xD.w, wr + 240);
    }
    z0 = gelu4(z0); z1 = gelu4(z1); z2 = gelu4(z2); z3 = gelu4(z3);
    z4 = gelu4(z4); z5 = gelu4(z5); z6 = gelu4(z6); z7 = gelu4(z7);
    z8 = gelu4(z8); z9 = gelu4(z9); za = gelu4(za); zb = gelu4(zb);
    zc = gelu4(zc); zd = gelu4(zd); ze = gelu4(ze); zf = gelu4(zf);

    float4* ho = (float4*)(h1_out + (size_t)b * EMB);
    ho[0] = z0;  ho[1] = z1;  ho[2] = z2;  ho[3] = z3;
    ho[4] = z4;  ho[5] = z5;  ho[6] = z6;  ho[7] = z7;
    ho[8] = z8;  ho[9] = z9;  ho[10] = za; ho[11] = zb;
    ho[12] = zc; ho[13] = zd; ho[14] = ze; ho[15] = zf;
}

// ---------------- fc2 + gelu + LN + gate + top2; h1 -> h in place ----------------
__global__ __launch_bounds__(256, 2) void k_fc2gate(
    float* h,                                 // in: h1, out: h (same buffer, own row)
    const int* __restrict__ uid,
    const float* __restrict__ w2, const float* __restrict__ b2,
    const float* __restrict__ gam, const float* __restrict__ bet,
    const float* __restrict__ A, const float* __restrict__ gb,
    int* __restrict__ top_e, float* __restrict__ top_w, int* __restrict__ hist)
{
    __shared__ __align__(16) float4 s_w2[EMB * 16];    // 16 KB [d][k4]
    __shared__ __align__(16) float4 s_b2[16], s_ga[16], s_be[16];
    __shared__ float s_gb[NE];
    __shared__ int s_hist[NE];

    const int tid = threadIdx.x;
    {
        const float4* g2 = (const float4*)w2;
        for (int i = tid; i < EMB * 16; i += 256) s_w2[i] = g2[i];
        if (tid < 16) {
            s_b2[tid] = ((const float4*)b2)[tid];
            s_ga[tid] = ((const float4*)gam)[tid];
            s_be[tid] = ((const float4*)bet)[tid];
        }
        if (tid < NE) { s_gb[tid] = gb[tid]; s_hist[tid] = 0; }
    }
    __syncthreads();

    const int b = blockIdx.x * 256 + tid;
    float4* hp = (float4*)(h + (size_t)b * EMB);

    float4 z0 = s_b2[0],  z1 = s_b2[1],  z2 = s_b2[2],  z3 = s_b2[3];
    float4 z4 = s_b2[4],  z5 = s_b2[5],  z6 = s_b2[6],  z7 = s_b2[7];
    float4 z8 = s_b2[8],  z9 = s_b2[9],  za = s_b2[10], zb = s_b2[11];
    float4 zc = s_b2[12], zd = s_b2[13], ze = s_b2[14], zf = s_b2[15];
#pragma unroll 1
    for (int t = 0; t < 4; ++t) {
        float4 hA = hp[4*t+0], hB = hp[4*t+1], hC = hp[4*t+2], hD = hp[4*t+3];
        const float4* wr = s_w2 + (t * 16) * 16;
        FMA16Z(hA.x, wr);       FMA16Z(hA.y, wr + 16);  FMA16Z(hA.z, wr + 32);  FMA16Z(hA.w, wr + 48);
        FMA16Z(hB.x, wr + 64);  FMA16Z(hB.y, wr + 80);  FMA16Z(hB.z, wr + 96);  FMA16Z(hB.w, wr + 112);
        FMA16Z(hC.x, wr + 128); FMA16Z(hC.y, wr + 144); FMA16Z(hC.z, wr + 160); FMA16Z(hC.w, wr + 176);
        FMA16Z(hD.x, wr + 192); FMA16Z(hD.y, wr + 208); FMA16Z(hD.z, wr + 224); FMA16Z(hD.w, wr + 240);
    }
    z0 = gelu4(z0); z1 = gelu4(z1); z2 = gelu4(z2); z3 = gelu4(z3);
    z4 = gelu4(z4); z5 = gelu4(z5); z6 = gelu4(z6); z7 = gelu4(z7);
    z8 = gelu4(z8); z9 = gelu4(z9); za = gelu4(za); zb = gelu4(zb);
    zc = gelu4(zc); zd = gelu4(zd); ze = gelu4(ze); zf = gelu4(zf);

    // LayerNorm
    float4 sA = add4(add4(add4(z0, z1), add4(z2, z3)), add4(add4(z4, z5), add4(z6, z7)));
    float4 sB = add4(add4(add4(z8, z9), add4(za, zb)), add4(add4(zc, zd), add4(ze, zf)));
    float4 sS = add4(sA, sB);
    float mu = (sS.x + sS.y + sS.z + sS.w) * (1.0f / 64.0f);
    float4 vv = make_float4(0.f, 0.f, 0.f, 0.f);
#define BBV(Z) do { float4 d4; d4.x = (Z).x - mu; d4.y = (Z).y - mu; d4.z = (Z).z - mu; d4.w = (Z).w - mu; \
                    vv = ffma4(d4, d4, vv); } while (0)
    BBV(z0); BBV(z1); BBV(z2); BBV(z3); BBV(z4); BBV(z5); BBV(z6); BBV(z7);
    BBV(z8); BBV(z9); BBV(za); BBV(zb); BBV(zc); BBV(zd); BBV(ze); BBV(zf);
#undef BBV
    float var = (vv.x + vv.y + vv.z + vv.w) * (1.0f / 64.0f);
    float inv = 1.0f / sqrtf(var + 1e-5f);
    z0 = ln4(z0, mu, inv, s_ga[0],  s_be[0]);
    z1 = ln4(z1, mu, inv, s_ga[1],  s_be[1]);
    z2 = ln4(z2, mu, inv, s_ga[2],  s_be[2]);
    z3 = ln4(z3, mu, inv, s_ga[3],  s_be[3]);
    z4 = ln4(z4, mu, inv, s_ga[4],  s_be[4]);
    z5 = ln4(z5, mu, inv, s_ga[5],  s_be[5]);
    z6 = ln4(z6, mu, inv, s_ga[6],  s_be[6]);
    z7 = ln4(z7, mu, inv, s_ga[7],  s_be[7]);
    z8 = ln4(z8, mu, inv, s_ga[8],  s_be[8]);
    z9 = ln4(z9, mu, inv, s_ga[9],  s_be[9]);
    za = ln4(za, mu, inv, s_ga[10], s_be[10]);
    zb = ln4(zb, mu, inv, s_ga[11], s_be[11]);
    zc = ln4(zc, mu, inv, s_ga[12], s_be[12]);
    zd = ln4(zd, mu, inv, s_ga[13], s_be[13]);
    ze = ln4(ze, mu, inv, s_ga[14], s_be[14]);
    zf = ln4(zf, mu, inv, s_ga[15], s_be[15]);

    hp[0] = z0;  hp[1] = z1;  hp[2] = z2;  hp[3] = z3;
    hp[4] = z4;  hp[5] = z5;  hp[6] = z6;  hp[7] = z7;
    hp[8] = z8;  hp[9] = z9;  hp[10] = za; hp[11] = zb;
    hp[12] = zc; hp[13] = zd; hp[14] = ze; hp[15] = zf;

    // gate + running top-2 (lowest index wins ties)
    const int u = uid[b];
    const float4* Ap = (const float4*)(A + (size_t)u * NE * EMB);
    float m0 = -1e30f, m1 = -1e30f;
    int i0 = 0, i1 = 0;
#pragma unroll 1
    for (int e = 0; e < NE; ++e) {
        const float4* ap = Ap + e * 16;
        float4 ac = make_float4(0.f, 0.f, 0.f, 0.f);
        ac = ffma4(z0, ap[0],  ac); ac = ffma4(z1, ap[1],  ac);
        ac = ffma4(z2, ap[2],  ac); ac = ffma4(z3, ap[3],  ac);
        ac = ffma4(z4, ap[4],  ac); ac = ffma4(z5, ap[5],  ac);
        ac = ffma4(z6, ap[6],  ac); ac = ffma4(z7, ap[7],  ac);
        ac = ffma4(z8, ap[8],  ac); ac = ffma4(z9, ap[9],  ac);
        ac = ffma4(za, ap[10], ac); ac = ffma4(zb, ap[11], ac);
        ac = ffma4(zc, ap[12], ac); ac = ffma4(zd, ap[13], ac);
        ac = ffma4(ze, ap[14], ac); ac = ffma4(zf, ap[15], ac);
        float ge = ((ac.x + ac.y) + (ac.z + ac.w)) + s_gb[e];
        if (ge > m0)      { m1 = m0; i1 = i0; m0 = ge; i0 = e; }
        else if (ge > m1) { m1 = ge; i1 = e; }
    }
    float t = expf(m1 - m0);
    float w0n = 1.0f / (1.0f + t);
    float w1n = t / (1.0f + t);

    top_e[2*b+0] = i0; top_w[2*b+0] = w0n;
    top_e[2*b+1] = i1; top_w[2*b+1] = w1n;
    atomicAdd(&s_hist[i0], 1);
    atomicAdd(&s_hist[i1], 1);
    __syncthreads();
    if (tid < NE) atomicAdd(&hist[tid], s_hist[tid]);
}

// ---------------- tiny exclusive scan ----------------
__global__ void k_scan(const int* __restrict__ hist, int* __restrict__ offs, int* __restrict__ cur)
{
    if (blockIdx.x == 0 && threadIdx.x == 0) {
        int acc = 0;
        for (int e = 0; e < NE; ++e) { offs[e] = acc; cur[e] = acc; acc += hist[e]; }
    }
}

// ---------------- block-aggregated scatter ----------------
__global__ __launch_bounds__(256) void k_scatter(
    const int* __restrict__ top_e, const float* __restrict__ top_w,
    int* __restrict__ cur, int* __restrict__ pair_b, float* __restrict__ pair_w)
{
    __shared__ int lh[NE];
    __shared__ int lbase[NE];
    const int tid = threadIdx.x;
    if (tid < NE) lh[tid] = 0;
    __syncthreads();

    const int b = blockIdx.x * 256 + tid;
    const int e0 = top_e[2*b+0];
    const int e1 = top_e[2*b+1];
    atomicAdd(&lh[e0], 1);
    atomicAdd(&lh[e1], 1);
    __syncthreads();
    if (tid < NE) {
        lbase[tid] = atomicAdd(&cur[tid], lh[tid]);
        lh[tid] = 0;
    }
    __syncthreads();
    int r0 = atomicAdd(&lh[e0], 1);
    int p0 = lbase[e0] + r0;
    pair_b[p0] = b; pair_w[p0] = top_w[2*b+0];
    int r1 = atomicAdd(&lh[e1], 1);
    int p1 = lbase[e1] + r1;
    pair_b[p1] = b; pair_w[p1] = top_w[2*b+1];
}

// ---------------- expert: z(64) in regs, h streamed; VGPR cap 128, 16 waves/CU ----------------
#define EXP_BX 64
__global__ __launch_bounds__(256, 2) void k_expert(
    const float* __restrict__ h,
    const int* __restrict__ pair_b, const float* __restrict__ pair_w,
    const int* __restrict__ hist, const int* __restrict__ offs,
    const float* __restrict__ ew1, const float* __restrict__ eb1,
    const float* __restrict__ eg, const float* __restrict__ ebeta,
    const float* __restrict__ ew2, const float* __restrict__ eb2,
    float* __restrict__ out)
{
    const int e = blockIdx.y;
    const int cnt = hist[e];
    if ((int)(blockIdx.x * 256) >= cnt) return;

    __shared__ __align__(16) float4 s_w1[EMB * 16];    // 16 KB [d][k4]
    __shared__ __align__(16) float4 s_w2[EMB * 3];     // 3 KB  [k][c4] padded 10->12
    __shared__ __align__(16) float4 s_b1[16], s_ga[16], s_be[16], s_b2[3];

    const int tid = threadIdx.x;
    {
        const float4* g1 = (const float4*)(ew1 + (size_t)e * EMB * EMB);
        for (int i = tid; i < EMB * 16; i += 256) s_w1[i] = g1[i];
        float* w2f = (float*)s_w2;
        for (int i = tid; i < EMB * 12; i += 256) {
            int k = i / 12, c = i - k * 12;
            w2f[i] = (c < NCLS) ? ew2[((size_t)e * EMB + k) * NCLS + c] : 0.0f;
        }
        if (tid < 16) {
            s_b1[tid] = ((const float4*)(eb1   + (size_t)e * EMB))[tid];
            s_ga[tid] = ((const float4*)(eg    + (size_t)e * EMB))[tid];
            s_be[tid] = ((const float4*)(ebeta + (size_t)e * EMB))[tid];
        }
        float* b2f = (float*)s_b2;
        if (tid < 12) b2f[tid] = (tid < NCLS) ? eb2[e * NCLS + tid] : 0.0f;
    }
    __syncthreads();

    const int base = offs[e];

    for (int lane = blockIdx.x * 256 + tid; lane < cnt; lane += EXP_BX * 256) {
        const int idx = base + lane;
        const int b = pair_b[idx];
        const float pw = pair_w[idx];

        const float4* hp = (const float4*)(h + (size_t)b * EMB);

        float4 z0 = s_b1[0],  z1 = s_b1[1],  z2 = s_b1[2],  z3 = s_b1[3];
        float4 z4 = s_b1[4],  z5 = s_b1[5],  z6 = s_b1[6],  z7 = s_b1[7];
        float4 z8 = s_b1[8],  z9 = s_b1[9],  za = s_b1[10], zb = s_b1[11];
        float4 zc = s_b1[12], zd = s_b1[13], ze = s_b1[14], zf = s_b1[15];
#pragma unroll 1
        for (int t = 0; t < 4; ++t) {
            float4 hA = hp[4*t+0], hB = hp[4*t+1], hC = hp[4*t+2], hD = hp[4*t+3];
            const float4* wr = s_w1 + (t * 16) * 16;
            FMA16Z(hA.x, wr);       FMA16Z(hA.y, wr + 16);  FMA16Z(hA.z, wr + 32);  FMA16Z(hA.w, wr + 48);
            FMA16Z(hB.x, wr + 64);  FMA16Z(hB.y, wr + 80);  FMA16Z(hB.z, wr + 96);  FMA16Z(hB.w, wr + 112);
            FMA16Z(hC.x, wr + 128); FMA16Z(hC.y, wr + 144); FMA16Z(hC.z, wr + 160); FMA16Z(hC.w, wr + 176);
            FMA16Z(hD.x, wr + 192); FMA16Z(hD.y, wr + 208); FMA16Z(hD.z, wr + 224); FMA16Z(hD.w, wr + 240);
        }
        z0 = gelu4(z0); z1 = gelu4(z1); z2 = gelu4(z2); z3 = gelu4(z3);
        z4 = gelu4(z4); z5 = gelu4(z5); z6 = gelu4(z6); z7 = gelu4(z7);
        z8 = gelu4(z8); z9 = gelu4(z9); za = gelu4(za); zb = gelu4(zb);
        zc = gelu4(zc); zd = gelu4(zd); ze = gelu4(ze); zf = gelu4(zf);

        float4 sA = add4(add4(add4(z0, z1), add4(z2, z3)), add4(add4(z4, z5), add4(z6, z7)));
        float4 sB = add4(add4(add4(z8, z9), add4(za, zb)), add4(add4(zc, zd), add4(ze, zf)));
        float4 sS = add4(sA, sB);
        float mu = (sS.x + sS.y + sS.z + sS.w) * (1.0f / 64.0f);
        float4 vv = make_float4(0.f, 0.f, 0.f, 0.f);
#define EXV(Z) do { float4 d4; d4.x = (Z).x - mu; d4.y = (Z).y - mu; d4.z = (Z).z - mu; d4.w = (Z).w - mu; \
                    vv = ffma4(d4, d4, vv); } while (0)
        EXV(z0); EXV(z1); EXV(z2); EXV(z3); EXV(z4); EXV(z5); EXV(z6); EXV(z7);
        EXV(z8); EXV(z9); EXV(za); EXV(zb); EXV(zc); EXV(zd); EXV(ze); EXV(zf);
#undef EXV
        float var = (vv.x + vv.y + vv.z + vv.w) * (1.0f / 64.0f);
        float inv = 1.0f / sqrtf(var + 1e-5f);
        z0 = ln4(z0, mu, inv, s_ga[0],  s_be[0]);
        z1 = ln4(z1, mu, inv, s_ga[1],  s_be[1]);
        z2 = ln4(z2, mu, inv, s_ga[2],  s_be[2]);
        z3 = ln4(z3, mu, inv, s_ga[3],  s_be[3]);
        z4 = ln4(z4, mu, inv, s_ga[4],  s_be[4]);
        z5 = ln4(z5, mu, inv, s_ga[5],  s_be[5]);
        z6 = ln4(z6, mu, inv, s_ga[6],  s_be[6]);
        z7 = ln4(z7, mu, inv, s_ga[7],  s_be[7]);
        z8 = ln4(z8, mu, inv, s_ga[8],  s_be[8]);
        z9 = ln4(z9, mu, inv, s_ga[9],  s_be[9]);
        za = ln4(za, mu, inv, s_ga[10], s_be[10]);
        zb = ln4(zb, mu, inv, s_ga[11], s_be[11]);
        zc = ln4(zc, mu, inv, s_ga[12], s_be[12]);
        zd = ln4(zd, mu, inv, s_ga[13], s_be[13]);
        ze = ln4(ze, mu, inv, s_ga[14], s_be[14]);
        zf = ln4(zf, mu, inv, s_ga[15], s_be[15]);

        float4 a0 = s_b2[0], a1 = s_b2[1], a2 = s_b2[2];
#define EXF2(ZQ, DB) do { \
        const float4* wr = s_w2 + (DB) * 3; \
        a0 = sfma4((ZQ).x, wr[0],  a0); a1 = sfma4((ZQ).x, wr[1],  a1); a2 = sfma4((ZQ).x, wr[2],  a2); \
        a0 = sfma4((ZQ).y, wr[3],  a0); a1 = sfma4((ZQ).y, wr[4],  a1); a2 = sfma4((ZQ).y, wr[5],  a2); \
        a0 = sfma4((ZQ).z, wr[6],  a0); a1 = sfma4((ZQ).z, wr[7],  a1); a2 = sfma4((ZQ).z, wr[8],  a2); \
        a0 = sfma4((ZQ).w, wr[9],  a0); a1 = sfma4((ZQ).w, wr[10], a1); a2 = sfma4((ZQ).w, wr[11], a2); \
} while (0)
        EXF2(z0, 0);  EXF2(z1, 4);  EXF2(z2, 8);  EXF2(z3, 12);
        EXF2(z4, 16); EXF2(z5, 20); EXF2(z6, 24); EXF2(z7, 28);
        EXF2(z8, 32); EXF2(z9, 36); EXF2(za, 40); EXF2(zb, 44);
        EXF2(zc, 48); EXF2(zd, 52); EXF2(ze, 56); EXF2(zf, 60);
#undef EXF2

        float* ob = out + (size_t)b * NCLS;
        atomicAdd(ob + 0, pw * a0.x);
        atomicAdd(ob + 1, pw * a0.y);
        atomicAdd(ob + 2, pw * a0.z);
        atomicAdd(ob + 3, pw * a0.w);
        atomicAdd(ob + 4, pw * a1.x);
        atomicAdd(ob + 5, pw * a1.y);
        atomicAdd(ob + 6, pw * a1.z);
        atomicAdd(ob + 7, pw * a1.w);
        atomicAdd(ob + 8, pw * a2.x);
        atomicAdd(ob + 9, pw * a2.y);
    }
}

extern "C" void kernel_launch(void* const* d_in, const int* in_sizes, int n_in,
                              void* d_out, int out_size, void* d_ws, size_t ws_size,
                              hipStream_t stream)
{
    (void)in_sizes; (void)n_in; (void)out_size; (void)ws_size;

    const float* x     = (const float*)d_in[0];
    const int*   uid   = (const int*)  d_in[1];
    const float* bb_w1 = (const float*)d_in[2];
    const float* bb_b1 = (const float*)d_in[3];
    const float* bb_w2 = (const float*)d_in[4];
    const float* bb_b2 = (const float*)d_in[5];
    const float* bb_g  = (const float*)d_in[6];
    const float* bb_be = (const float*)d_in[7];
    const float* gU    = (const float*)d_in[8];
    const float* gV    = (const float*)d_in[9];
    const float* gb    = (const float*)d_in[10];
    const float* e_w1  = (const float*)d_in[11];
    const float* e_b1  = (const float*)d_in[12];
    const float* e_g   = (const float*)d_in[13];
    const float* e_be  = (const float*)d_in[14];
    const float* e_w2  = (const float*)d_in[15];
    const float* e_b2  = (const float*)d_in[16];
    const float* ut    = (const float*)d_in[17];

    float* out = (float*)d_out;
    char*  ws  = (char*)d_ws;

    float* h      = (float*)(ws + OFF_H);
    float* A      = (float*)(ws + OFF_A);
    int*   top_e  = (int*)  (ws + OFF_TOPE);
    float* top_w  = (float*)(ws + OFF_TOPW);
    int*   pair_b = (int*)  (ws + OFF_PAIRB);
    float* pair_w = (float*)(ws + OFF_PAIRW);
    int*   hist   = (int*)  (ws + OFF_HIST);
    int*   offs   = (int*)  (ws + OFF_OFFS);
    int*   cur    = (int*)  (ws + OFF_CUR);

    hipMemsetAsync(out, 0, (size_t)BATCH * NCLS * sizeof(float), stream);
    hipMemsetAsync(hist, 0, NE * sizeof(int), stream);

    k_prep<<<(NUSERS * NE + 255) / 256, 256, 0, stream>>>(gU, gV, ut, A);
    k_fc1<<<BATCH / 256, 256, 0, stream>>>(x, bb_w1, bb_b1, h);
    k_fc2gate<<<BATCH / 256, 256, 0, stream>>>(h, uid, bb_w2, bb_b2, bb_g, bb_be,
                                               A, gb, top_e, top_w, hist);
    k_scan<<<1, 64, 0, stream>>>(hist, offs, cur);
    k_scatter<<<BATCH / 256, 256, 0, stream>>>(top_e, top_w, cur, pair_b, pair_w);
    dim3 eg(EXP_BX, NE);
    k_expert<<<eg, 256, 0, stream>>>(h, pair_b, pair_w, hist, offs,
                                     e_w1, e_b1, e_g, e_be, e_w2, e_b2, out);
}

// Round 11
// 384.316 us; speedup vs baseline: 1.4548x; 1.4253x over previous
//
#include <hip/hip_runtime.h>
#include <math.h>

#define BATCH   131072
#define IN_F    80
#define EMB     64
#define NE      16
#define RANK    8
#define UDIM    16
#define NCLS    10
#define NUSERS  1000

// ---- workspace layout (bytes) ----
#define OFF_H      0ull                 // BATCH*64 f32 (h1, then h in-place)
#define OFF_A      33554432ull          // NUSERS*16*64 f32
#define OFF_TOPE   37650432ull
#define OFF_TOPW   38699008ull
#define OFF_PAIRB  39747584ull
#define OFF_PAIRW  40796160ull
#define OFF_HIST   41844736ull
#define OFF_OFFS   41845760ull
#define OFF_CUR    41846784ull

__device__ __forceinline__ float gelu_f(float v) {
    return 0.5f * v * (1.0f + erff(v * 0.70710678118654752440f));
}
__device__ __forceinline__ float4 gelu4(float4 v) {
    v.x = gelu_f(v.x); v.y = gelu_f(v.y); v.z = gelu_f(v.z); v.w = gelu_f(v.w);
    return v;
}
__device__ __forceinline__ float4 sfma4(float s, float4 w, float4 a) {
    a.x = fmaf(s, w.x, a.x); a.y = fmaf(s, w.y, a.y);
    a.z = fmaf(s, w.z, a.z); a.w = fmaf(s, w.w, a.w);
    return a;
}
__device__ __forceinline__ float4 ffma4(float4 v, float4 w, float4 a) {
    a.x = fmaf(v.x, w.x, a.x); a.y = fmaf(v.y, w.y, a.y);
    a.z = fmaf(v.z, w.z, a.z); a.w = fmaf(v.w, w.w, a.w);
    return a;
}
__device__ __forceinline__ float4 add4(float4 a, float4 b) {
    a.x += b.x; a.y += b.y; a.z += b.z; a.w += b.w; return a;
}
__device__ __forceinline__ float4 ln4(float4 z, float mu, float inv, float4 g, float4 bb) {
    float4 r;
    r.x = fmaf((z.x - mu) * inv, g.x, bb.x);
    r.y = fmaf((z.y - mu) * inv, g.y, bb.y);
    r.z = fmaf((z.z - mu) * inv, g.z, bb.z);
    r.w = fmaf((z.w - mu) * inv, g.w, bb.w);
    return r;
}
__device__ __forceinline__ float4 shflx4(float4 a, int m) {
    float4 r;
    r.x = __shfl_xor(a.x, m, 64); r.y = __shfl_xor(a.y, m, 64);
    r.z = __shfl_xor(a.z, m, 64); r.w = __shfl_xor(a.w, m, 64);
    return r;
}

#define FMA16Z(S, WB) do { \
    z0 = sfma4((S), (WB)[0],  z0); z1 = sfma4((S), (WB)[1],  z1); \
    z2 = sfma4((S), (WB)[2],  z2); z3 = sfma4((S), (WB)[3],  z3); \
    z4 = sfma4((S), (WB)[4],  z4); z5 = sfma4((S), (WB)[5],  z5); \
    z6 = sfma4((S), (WB)[6],  z6); z7 = sfma4((S), (WB)[7],  z7); \
    z8 = sfma4((S), (WB)[8],  z8); z9 = sfma4((S), (WB)[9],  z9); \
    za = sfma4((S), (WB)[10], za); zb = sfma4((S), (WB)[11], zb); \
    zc = sfma4((S), (WB)[12], zc); zd = sfma4((S), (WB)[13], zd); \
    ze = sfma4((S), (WB)[14], ze); zf = sfma4((S), (WB)[15], zf); } while (0)

// ---------------- A[u][e][d] precompute ----------------
__global__ void k_prep(const float* __restrict__ gU, const float* __restrict__ gV,
                       const float* __restrict__ ut, float* __restrict__ A)
{
    int idx = blockIdx.x * 256 + threadIdx.x;
    if (idx >= NUSERS * NE) return;
    int u = idx / NE, e = idx - u * NE;

    const float4* up = (const float4*)(ut + (size_t)u * UDIM);
    float4 u0 = up[0], u1 = up[1], u2 = up[2], u3 = up[3];

    float4 va = make_float4(0.f, 0.f, 0.f, 0.f);
    float4 vb = make_float4(0.f, 0.f, 0.f, 0.f);
    const float4* gv4 = (const float4*)gV;
#define UVSTEP(UD, DD) do { \
        float4 g0 = gv4[(e * UDIM + (DD)) * 2 + 0]; \
        float4 g1 = gv4[(e * UDIM + (DD)) * 2 + 1]; \
        va = sfma4((UD), g0, va); vb = sfma4((UD), g1, vb); } while (0)
    UVSTEP(u0.x, 0);  UVSTEP(u0.y, 1);  UVSTEP(u0.z, 2);  UVSTEP(u0.w, 3);
    UVSTEP(u1.x, 4);  UVSTEP(u1.y, 5);  UVSTEP(u1.z, 6);  UVSTEP(u1.w, 7);
    UVSTEP(u2.x, 8);  UVSTEP(u2.y, 9);  UVSTEP(u2.z, 10); UVSTEP(u2.w, 11);
    UVSTEP(u3.x, 12); UVSTEP(u3.y, 13); UVSTEP(u3.z, 14); UVSTEP(u3.w, 15);
#undef UVSTEP

    const float4* gu4 = (const float4*)gU;
    float* Ao = A + ((size_t)u * NE + e) * EMB;
    for (int d = 0; d < EMB; ++d) {
        float4 q0 = gu4[(e * EMB + d) * 2 + 0];
        float4 q1 = gu4[(e * EMB + d) * 2 + 1];
        float a = 0.0f;
        a = fmaf(q0.x, va.x, a); a = fmaf(q0.y, va.y, a);
        a = fmaf(q0.z, va.z, a); a = fmaf(q0.w, va.w, a);
        a = fmaf(q1.x, vb.x, a); a = fmaf(q1.y, vb.y, a);
        a = fmaf(q1.z, vb.z, a); a = fmaf(q1.w, vb.w, a);
        Ao[d] = a;
    }
}

// ---------------- fc1: x streamed once, z(64) acc, gelu -> h1 (R8 config, validated) ----------------
__global__ __launch_bounds__(256) void k_fc1(
    const float* __restrict__ x,
    const float* __restrict__ w1, const float* __restrict__ b1,
    float* __restrict__ h1_out)
{
    __shared__ __align__(16) float4 s_w1[IN_F * 16];   // 20 KB [d][k4]
    __shared__ __align__(16) float4 s_b1[16];

    const int tid = threadIdx.x;
    {
        const float4* g1 = (const float4*)w1;
        for (int i = tid; i < IN_F * 16; i += 256) s_w1[i] = g1[i];
        if (tid < 16) s_b1[tid] = ((const float4*)b1)[tid];
    }
    __syncthreads();

    const int b = blockIdx.x * 256 + tid;
    const float4* xp = (const float4*)(x + (size_t)b * IN_F);

    float4 z0 = s_b1[0],  z1 = s_b1[1],  z2 = s_b1[2],  z3 = s_b1[3];
    float4 z4 = s_b1[4],  z5 = s_b1[5],  z6 = s_b1[6],  z7 = s_b1[7];
    float4 z8 = s_b1[8],  z9 = s_b1[9],  za = s_b1[10], zb = s_b1[11];
    float4 zc = s_b1[12], zd = s_b1[13], ze = s_b1[14], zf = s_b1[15];

#pragma unroll 1
    for (int t = 0; t < 5; ++t) {
        float4 xA = xp[4*t+0], xB = xp[4*t+1], xC = xp[4*t+2], xD = xp[4*t+3];
        const float4* wr = s_w1 + (t * 16) * 16;
        FMA16Z(xA.x, wr);       FMA16Z(xA.y, wr + 16);  FMA16Z(xA.z, wr + 32);  FMA16Z(xA.w, wr + 48);
        FMA16Z(xB.x, wr + 64);  FMA16Z(xB.y, wr + 80);  FMA16Z(xB.z, wr + 96);  FMA16Z(xB.w, wr + 112);
        FMA16Z(xC.x, wr + 128); FMA16Z(xC.y, wr + 144); FMA16Z(xC.z, wr + 160); FMA16Z(xC.w, wr + 176);
        FMA16Z(xD.x, wr + 192); FMA16Z(xD.y, wr + 208); FMA16Z(xD.z, wr + 224); FMA16Z(xD.w, wr + 240);
    }
    z0 = gelu4(z0); z1 = gelu4(z1); z2 = gelu4(z2); z3 = gelu4(z3);
    z4 = gelu4(z4); z5 = gelu4(z5); z6 = gelu4(z6); z7 = gelu4(z7);
    z8 = gelu4(z8); z9 = gelu4(z9); za = gelu4(za); zb = gelu4(zb);
    zc = gelu4(zc); zd = gelu4(zd); ze = gelu4(ze); zf = gelu4(zf);

    float4* ho = (float4*)(h1_out + (size_t)b * EMB);
    ho[0] = z0;  ho[1] = z1;  ho[2] = z2;  ho[3] = z3;
    ho[4] = z4;  ho[5] = z5;  ho[6] = z6;  ho[7] = z7;
    ho[8] = z8;  ho[9] = z9;  ho[10] = za; ho[11] = zb;
    ho[12] = zc; ho[13] = zd; ho[14] = ze; ho[15] = zf;
}

// ---------------- fc2 + gelu + LN + gate + top2; h1 -> h in place (R8 config) ----------------
__global__ __launch_bounds__(256) void k_fc2gate(
    float* h,
    const int* __restrict__ uid,
    const float* __restrict__ w2, const float* __restrict__ b2,
    const float* __restrict__ gam, const float* __restrict__ bet,
    const float* __restrict__ A, const float* __restrict__ gb,
    int* __restrict__ top_e, float* __restrict__ top_w, int* __restrict__ hist)
{
    __shared__ __align__(16) float4 s_w2[EMB * 16];    // 16 KB [d][k4]
    __shared__ __align__(16) float4 s_b2[16], s_ga[16], s_be[16];
    __shared__ float s_gb[NE];
    __shared__ int s_hist[NE];

    const int tid = threadIdx.x;
    {
        const float4* g2 = (const float4*)w2;
        for (int i = tid; i < EMB * 16; i += 256) s_w2[i] = g2[i];
        if (tid < 16) {
            s_b2[tid] = ((const float4*)b2)[tid];
            s_ga[tid] = ((const float4*)gam)[tid];
            s_be[tid] = ((const float4*)bet)[tid];
        }
        if (tid < NE) { s_gb[tid] = gb[tid]; s_hist[tid] = 0; }
    }
    __syncthreads();

    const int b = blockIdx.x * 256 + tid;
    float4* hp = (float4*)(h + (size_t)b * EMB);

    float4 z0 = s_b2[0],  z1 = s_b2[1],  z2 = s_b2[2],  z3 = s_b2[3];
    float4 z4 = s_b2[4],  z5 = s_b2[5],  z6 = s_b2[6],  z7 = s_b2[7];
    float4 z8 = s_b2[8],  z9 = s_b2[9],  za = s_b2[10], zb = s_b2[11];
    float4 zc = s_b2[12], zd = s_b2[13], ze = s_b2[14], zf = s_b2[15];
#pragma unroll 1
    for (int t = 0; t < 4; ++t) {
        float4 hA = hp[4*t+0], hB = hp[4*t+1], hC = hp[4*t+2], hD = hp[4*t+3];
        const float4* wr = s_w2 + (t * 16) * 16;
        FMA16Z(hA.x, wr);       FMA16Z(hA.y, wr + 16);  FMA16Z(hA.z, wr + 32);  FMA16Z(hA.w, wr + 48);
        FMA16Z(hB.x, wr + 64);  FMA16Z(hB.y, wr + 80);  FMA16Z(hB.z, wr + 96);  FMA16Z(hB.w, wr + 112);
        FMA16Z(hC.x, wr + 128); FMA16Z(hC.y, wr + 144); FMA16Z(hC.z, wr + 160); FMA16Z(hC.w, wr + 176);
        FMA16Z(hD.x, wr + 192); FMA16Z(hD.y, wr + 208); FMA16Z(hD.z, wr + 224); FMA16Z(hD.w, wr + 240);
    }
    z0 = gelu4(z0); z1 = gelu4(z1); z2 = gelu4(z2); z3 = gelu4(z3);
    z4 = gelu4(z4); z5 = gelu4(z5); z6 = gelu4(z6); z7 = gelu4(z7);
    z8 = gelu4(z8); z9 = gelu4(z9); za = gelu4(za); zb = gelu4(zb);
    zc = gelu4(zc); zd = gelu4(zd); ze = gelu4(ze); zf = gelu4(zf);

    // LayerNorm
    float4 sA = add4(add4(add4(z0, z1), add4(z2, z3)), add4(add4(z4, z5), add4(z6, z7)));
    float4 sB = add4(add4(add4(z8, z9), add4(za, zb)), add4(add4(zc, zd), add4(ze, zf)));
    float4 sS = add4(sA, sB);
    float mu = (sS.x + sS.y + sS.z + sS.w) * (1.0f / 64.0f);
    float4 vv = make_float4(0.f, 0.f, 0.f, 0.f);
#define BBV(Z) do { float4 d4; d4.x = (Z).x - mu; d4.y = (Z).y - mu; d4.z = (Z).z - mu; d4.w = (Z).w - mu; \
                    vv = ffma4(d4, d4, vv); } while (0)
    BBV(z0); BBV(z1); BBV(z2); BBV(z3); BBV(z4); BBV(z5); BBV(z6); BBV(z7);
    BBV(z8); BBV(z9); BBV(za); BBV(zb); BBV(zc); BBV(zd); BBV(ze); BBV(zf);
#undef BBV
    float var = (vv.x + vv.y + vv.z + vv.w) * (1.0f / 64.0f);
    float inv = 1.0f / sqrtf(var + 1e-5f);
    z0 = ln4(z0, mu, inv, s_ga[0],  s_be[0]);
    z1 = ln4(z1, mu, inv, s_ga[1],  s_be[1]);
    z2 = ln4(z2, mu, inv, s_ga[2],  s_be[2]);
    z3 = ln4(z3, mu, inv, s_ga[3],  s_be[3]);
    z4 = ln4(z4, mu, inv, s_ga[4],  s_be[4]);
    z5 = ln4(z5, mu, inv, s_ga[5],  s_be[5]);
    z6 = ln4(z6, mu, inv, s_ga[6],  s_be[6]);
    z7 = ln4(z7, mu, inv, s_ga[7],  s_be[7]);
    z8 = ln4(z8, mu, inv, s_ga[8],  s_be[8]);
    z9 = ln4(z9, mu, inv, s_ga[9],  s_be[9]);
    za = ln4(za, mu, inv, s_ga[10], s_be[10]);
    zb = ln4(zb, mu, inv, s_ga[11], s_be[11]);
    zc = ln4(zc, mu, inv, s_ga[12], s_be[12]);
    zd = ln4(zd, mu, inv, s_ga[13], s_be[13]);
    ze = ln4(ze, mu, inv, s_ga[14], s_be[14]);
    zf = ln4(zf, mu, inv, s_ga[15], s_be[15]);

    hp[0] = z0;  hp[1] = z1;  hp[2] = z2;  hp[3] = z3;
    hp[4] = z4;  hp[5] = z5;  hp[6] = z6;  hp[7] = z7;
    hp[8] = z8;  hp[9] = z9;  hp[10] = za; hp[11] = zb;
    hp[12] = zc; hp[13] = zd; hp[14] = ze; hp[15] = zf;

    // gate + running top-2 (lowest index wins ties)
    const int u = uid[b];
    const float4* Ap = (const float4*)(A + (size_t)u * NE * EMB);
    float m0 = -1e30f, m1 = -1e30f;
    int i0 = 0, i1 = 0;
#pragma unroll 1
    for (int e = 0; e < NE; ++e) {
        const float4* ap = Ap + e * 16;
        float4 ac = make_float4(0.f, 0.f, 0.f, 0.f);
        ac = ffma4(z0, ap[0],  ac); ac = ffma4(z1, ap[1],  ac);
        ac = ffma4(z2, ap[2],  ac); ac = ffma4(z3, ap[3],  ac);
        ac = ffma4(z4, ap[4],  ac); ac = ffma4(z5, ap[5],  ac);
        ac = ffma4(z6, ap[6],  ac); ac = ffma4(z7, ap[7],  ac);
        ac = ffma4(z8, ap[8],  ac); ac = ffma4(z9, ap[9],  ac);
        ac = ffma4(za, ap[10], ac); ac = ffma4(zb, ap[11], ac);
        ac = ffma4(zc, ap[12], ac); ac = ffma4(zd, ap[13], ac);
        ac = ffma4(ze, ap[14], ac); ac = ffma4(zf, ap[15], ac);
        float ge = ((ac.x + ac.y) + (ac.z + ac.w)) + s_gb[e];
        if (ge > m0)      { m1 = m0; i1 = i0; m0 = ge; i0 = e; }
        else if (ge > m1) { m1 = ge; i1 = e; }
    }
    float t = expf(m1 - m0);
    float w0n = 1.0f / (1.0f + t);
    float w1n = t / (1.0f + t);

    top_e[2*b+0] = i0; top_w[2*b+0] = w0n;
    top_e[2*b+1] = i1; top_w[2*b+1] = w1n;
    atomicAdd(&s_hist[i0], 1);
    atomicAdd(&s_hist[i1], 1);
    __syncthreads();
    if (tid < NE) atomicAdd(&hist[tid], s_hist[tid]);
}

// ---------------- tiny exclusive scan ----------------
__global__ void k_scan(const int* __restrict__ hist, int* __restrict__ offs, int* __restrict__ cur)
{
    if (blockIdx.x == 0 && threadIdx.x == 0) {
        int acc = 0;
        for (int e = 0; e < NE; ++e) { offs[e] = acc; cur[e] = acc; acc += hist[e]; }
    }
}

// ---------------- block-aggregated scatter ----------------
__global__ __launch_bounds__(256) void k_scatter(
    const int* __restrict__ top_e, const float* __restrict__ top_w,
    int* __restrict__ cur, int* __restrict__ pair_b, float* __restrict__ pair_w)
{
    __shared__ int lh[NE];
    __shared__ int lbase[NE];
    const int tid = threadIdx.x;
    if (tid < NE) lh[tid] = 0;
    __syncthreads();

    const int b = blockIdx.x * 256 + tid;
    const int e0 = top_e[2*b+0];
    const int e1 = top_e[2*b+1];
    atomicAdd(&lh[e0], 1);
    atomicAdd(&lh[e1], 1);
    __syncthreads();
    if (tid < NE) {
        lbase[tid] = atomicAdd(&cur[tid], lh[tid]);
        lh[tid] = 0;
    }
    __syncthreads();
    int r0 = atomicAdd(&lh[e0], 1);
    int p0 = lbase[e0] + r0;
    pair_b[p0] = b; pair_w[p0] = top_w[2*b+0];
    int r1 = atomicAdd(&lh[e1], 1);
    int p1 = lbase[e1] + r1;
    pair_b[p1] = b; pair_w[p1] = top_w[2*b+1];
}

// ---------------- expert: 4 lanes per pair, each lane computes 16 of 64 z outputs ----------------
// Live ~60 floats/thread -> (256,2) cap 128 is safe; 4x shorter FMA chain per wave.
// h loads: 4 lanes of a group issue identical addresses -> coalescer merges (no extra traffic).
// LN mean/var + fc2 partials combined with 2-step __shfl_xor (masks 1,2) inside the 4-lane group.
#define EXP_BX 128
__global__ __launch_bounds__(256, 2) void k_expert(
    const float* __restrict__ h,
    const int* __restrict__ pair_b, const float* __restrict__ pair_w,
    const int* __restrict__ hist, const int* __restrict__ offs,
    const float* __restrict__ ew1, const float* __restrict__ eb1,
    const float* __restrict__ eg, const float* __restrict__ ebeta,
    const float* __restrict__ ew2, const float* __restrict__ eb2,
    float* __restrict__ out)
{
    const int e = blockIdx.y;
    const int cnt = hist[e];
    if ((int)(blockIdx.x * 64) >= cnt) return;   // 64 pairs per block-iteration

    __shared__ __align__(16) float4 s_w1[EMB * 16];    // 16 KB [d][k4]
    __shared__ __align__(16) float4 s_w2[EMB * 3];     // 3 KB  [k][c4] padded 10->12
    __shared__ __align__(16) float4 s_b1[16], s_ga[16], s_be[16], s_b2[3];

    const int tid = threadIdx.x;
    {
        const float4* g1 = (const float4*)(ew1 + (size_t)e * EMB * EMB);
        for (int i = tid; i < EMB * 16; i += 256) s_w1[i] = g1[i];
        float* w2f = (float*)s_w2;
        for (int i = tid; i < EMB * 12; i += 256) {
            int k = i / 12, c = i - k * 12;
            w2f[i] = (c < NCLS) ? ew2[((size_t)e * EMB + k) * NCLS + c] : 0.0f;
        }
        if (tid < 16) {
            s_b1[tid] = ((const float4*)(eb1   + (size_t)e * EMB))[tid];
            s_ga[tid] = ((const float4*)(eg    + (size_t)e * EMB))[tid];
            s_be[tid] = ((const float4*)(ebeta + (size_t)e * EMB))[tid];
        }
        float* b2f = (float*)s_b2;
        if (tid < 12) b2f[tid] = (tid < NCLS) ? eb2[e * NCLS + tid] : 0.0f;
    }
    __syncthreads();

    const int base = offs[e];
    const int q  = tid & 3;       // output quarter (z[16q..16q+16))
    const int pl = tid >> 2;      // pair slot within block (0..63)

    for (int p0 = blockIdx.x * 64; p0 < cnt; p0 += EXP_BX * 64) {
        const int pr = p0 + pl;
        if (pr >= cnt) continue;                 // whole 4-lane group inactive together
        const int idx = base + pr;
        const int b = pair_b[idx];
        const float pw = pair_w[idx];

        const float4* hp = (const float4*)(h + (size_t)b * EMB);

        // fc1 quarter: z[16q..16q+16) in 4 named float4; d ascending (order-preserving)
        float4 z0 = s_b1[q*4+0], z1 = s_b1[q*4+1], z2 = s_b1[q*4+2], z3 = s_b1[q*4+3];
#define FMA4Q(S, WB) do { \
        z0 = sfma4((S), (WB)[0], z0); z1 = sfma4((S), (WB)[1], z1); \
        z2 = sfma4((S), (WB)[2], z2); z3 = sfma4((S), (WB)[3], z3); } while (0)
#pragma unroll 1
        for (int t = 0; t < 4; ++t) {
            float4 hA = hp[4*t+0], hB = hp[4*t+1], hC = hp[4*t+2], hD = hp[4*t+3];
            const float4* wr = s_w1 + (t * 16) * 16 + q * 4;
            FMA4Q(hA.x, wr + 0*16);  FMA4Q(hA.y, wr + 1*16);  FMA4Q(hA.z, wr + 2*16);  FMA4Q(hA.w, wr + 3*16);
            FMA4Q(hB.x, wr + 4*16);  FMA4Q(hB.y, wr + 5*16);  FMA4Q(hB.z, wr + 6*16);  FMA4Q(hB.w, wr + 7*16);
            FMA4Q(hC.x, wr + 8*16);  FMA4Q(hC.y, wr + 9*16);  FMA4Q(hC.z, wr + 10*16); FMA4Q(hC.w, wr + 11*16);
            FMA4Q(hD.x, wr + 12*16); FMA4Q(hD.y, wr + 13*16); FMA4Q(hD.z, wr + 14*16); FMA4Q(hD.w, wr + 15*16);
        }
#undef FMA4Q
        z0 = gelu4(z0); z1 = gelu4(z1); z2 = gelu4(z2); z3 = gelu4(z3);

        // LayerNorm: group butterfly reduce (masks 1,2 stay within 4-lane group)
        float4 sA = add4(add4(z0, z1), add4(z2, z3));
        float sl = (sA.x + sA.y) + (sA.z + sA.w);
        sl += __shfl_xor(sl, 1, 64);
        sl += __shfl_xor(sl, 2, 64);
        float mu = sl * (1.0f / 64.0f);

        float4 vv = make_float4(0.f, 0.f, 0.f, 0.f);
#define EXV(Z) do { float4 d4; d4.x = (Z).x - mu; d4.y = (Z).y - mu; d4.z = (Z).z - mu; d4.w = (Z).w - mu; \
                    vv = ffma4(d4, d4, vv); } while (0)
        EXV(z0); EXV(z1); EXV(z2); EXV(z3);
#undef EXV
        float vl = (vv.x + vv.y) + (vv.z + vv.w);
        vl += __shfl_xor(vl, 1, 64);
        vl += __shfl_xor(vl, 2, 64);
        float var = vl * (1.0f / 64.0f);
        float inv = 1.0f / sqrtf(var + 1e-5f);

        z0 = ln4(z0, mu, inv, s_ga[q*4+0], s_be[q*4+0]);
        z1 = ln4(z1, mu, inv, s_ga[q*4+1], s_be[q*4+1]);
        z2 = ln4(z2, mu, inv, s_ga[q*4+2], s_be[q*4+2]);
        z3 = ln4(z3, mu, inv, s_ga[q*4+3], s_be[q*4+3]);

        // fc2 partial over own k-quarter (k = 16q + i, i ascending)
        float4 a0 = make_float4(0.f, 0.f, 0.f, 0.f);
        float4 a1 = make_float4(0.f, 0.f, 0.f, 0.f);
        float4 a2 = make_float4(0.f, 0.f, 0.f, 0.f);
#define EXF2(S, I) do { \
        const float4* wr = s_w2 + (q * 16 + (I)) * 3; \
        a0 = sfma4((S), wr[0], a0); a1 = sfma4((S), wr[1], a1); a2 = sfma4((S), wr[2], a2); } while (0)
        EXF2(z0.x, 0);  EXF2(z0.y, 1);  EXF2(z0.z, 2);  EXF2(z0.w, 3);
        EXF2(z1.x, 4);  EXF2(z1.y, 5);  EXF2(z1.z, 6);  EXF2(z1.w, 7);
        EXF2(z2.x, 8);  EXF2(z2.y, 9);  EXF2(z2.z, 10); EXF2(z2.w, 11);
        EXF2(z3.x, 12); EXF2(z3.y, 13); EXF2(z3.z, 14); EXF2(z3.w, 15);
#undef EXF2

        // combine quarters (butterfly allreduce within group)
        a0 = add4(a0, shflx4(a0, 1)); a0 = add4(a0, shflx4(a0, 2));
        a1 = add4(a1, shflx4(a1, 1)); a1 = add4(a1, shflx4(a1, 2));
        a2 = add4(a2, shflx4(a2, 1)); a2 = add4(a2, shflx4(a2, 2));

        if (q == 0) {
            a0 = add4(a0, s_b2[0]); a1 = add4(a1, s_b2[1]); a2 = add4(a2, s_b2[2]);
            float* ob = out + (size_t)b * NCLS;
            atomicAdd(ob + 0, pw * a0.x);
            atomicAdd(ob + 1, pw * a0.y);
            atomicAdd(ob + 2, pw * a0.z);
            atomicAdd(ob + 3, pw * a0.w);
            atomicAdd(ob + 4, pw * a1.x);
            atomicAdd(ob + 5, pw * a1.y);
            atomicAdd(ob + 6, pw * a1.z);
            atomicAdd(ob + 7, pw * a1.w);
            atomicAdd(ob + 8, pw * a2.x);
            atomicAdd(ob + 9, pw * a2.y);
        }
    }
}

extern "C" void kernel_launch(void* const* d_in, const int* in_sizes, int n_in,
                              void* d_out, int out_size, void* d_ws, size_t ws_size,
                              hipStream_t stream)
{
    (void)in_sizes; (void)n_in; (void)out_size; (void)ws_size;

    const float* x     = (const float*)d_in[0];
    const int*   uid   = (const int*)  d_in[1];
    const float* bb_w1 = (const float*)d_in[2];
    const float* bb_b1 = (const float*)d_in[3];
    const float* bb_w2 = (const float*)d_in[4];
    const float* bb_b2 = (const float*)d_in[5];
    const float* bb_g  = (const float*)d_in[6];
    const float* bb_be = (const float*)d_in[7];
    const float* gU    = (const float*)d_in[8];
    const float* gV    = (const float*)d_in[9];
    const float* gb    = (const float*)d_in[10];
    const float* e_w1  = (const float*)d_in[11];
    const float* e_b1  = (const float*)d_in[12];
    const float* e_g   = (const float*)d_in[13];
    const float* e_be  = (const float*)d_in[14];
    const float* e_w2  = (const float*)d_in[15];
    const float* e_b2  = (const float*)d_in[16];
    const float* ut    = (const float*)d_in[17];

    float* out = (float*)d_out;
    char*  ws  = (char*)d_ws;

    float* h      = (float*)(ws + OFF_H);
    float* A      = (float*)(ws + OFF_A);
    int*   top_e  = (int*)  (ws + OFF_TOPE);
    float* top_w  = (float*)(ws + OFF_TOPW);
    int*   pair_b = (int*)  (ws + OFF_PAIRB);
    float* pair_w = (float*)(ws + OFF_PAIRW);
    int*   hist   = (int*)  (ws + OFF_HIST);
    int*   offs   = (int*)  (ws + OFF_OFFS);
    int*   cur    = (int*)  (ws + OFF_CUR);

    hipMemsetAsync(out, 0, (size_t)BATCH * NCLS * sizeof(float), stream);
    hipMemsetAsync(hist, 0, NE * sizeof(int), stream);

    k_prep<<<(NUSERS * NE + 255) / 256, 256, 0, stream>>>(gU, gV, ut, A);
    k_fc1<<<BATCH / 256, 256, 0, stream>>>(x, bb_w1, bb_b1, h);
    k_fc2gate<<<BATCH / 256, 256, 0, stream>>>(h, uid, bb_w2, bb_b2, bb_g, bb_be,
                                               A, gb, top_e, top_w, hist);
    k_scan<<<1, 64, 0, stream>>>(hist, offs, cur);
    k_scatter<<<BATCH / 256, 256, 0, stream>>>(top_e, top_w, cur, pair_b, pair_w);
    dim3 eg(EXP_BX, NE);
    k_expert<<<eg, 256, 0, stream>>>(h, pair_b, pair_w, hist, offs,
                                     e_w1, e_b1, e_g, e_be, e_w2, e_b2, out);
}

// Round 13
// 308.292 us; speedup vs baseline: 1.8136x; 1.2466x over previous
//
#include <hip/hip_runtime.h>
#include <math.h>

#define BATCH   131072
#define IN_F    80
#define EMB     64
#define NE      16
#define RANK    8
#define UDIM    16
#define NCLS    10
#define NUSERS  1000

// ---- workspace layout (bytes) ----
#define OFF_H      0ull                 // BATCH*64 f32 (h1, then h in-place)
#define OFF_A      33554432ull          // NUSERS*16*64 f32
#define OFF_TOPE   37650432ull
#define OFF_TOPW   38699008ull
#define OFF_PAIRB  39747584ull
#define OFF_PAIRW  40796160ull
#define OFF_HIST   41844736ull
#define OFF_OFFS   41845760ull
#define OFF_CUR    41846784ull

__device__ __forceinline__ float gelu_f(float v) {
    return 0.5f * v * (1.0f + erff(v * 0.70710678118654752440f));
}
__device__ __forceinline__ float4 gelu4(float4 v) {
    v.x = gelu_f(v.x); v.y = gelu_f(v.y); v.z = gelu_f(v.z); v.w = gelu_f(v.w);
    return v;
}
__device__ __forceinline__ float4 sfma4(float s, float4 w, float4 a) {
    a.x = fmaf(s, w.x, a.x); a.y = fmaf(s, w.y, a.y);
    a.z = fmaf(s, w.z, a.z); a.w = fmaf(s, w.w, a.w);
    return a;
}
__device__ __forceinline__ float4 ffma4(float4 v, float4 w, float4 a) {
    a.x = fmaf(v.x, w.x, a.x); a.y = fmaf(v.y, w.y, a.y);
    a.z = fmaf(v.z, w.z, a.z); a.w = fmaf(v.w, w.w, a.w);
    return a;
}
__device__ __forceinline__ float4 add4(float4 a, float4 b) {
    a.x += b.x; a.y += b.y; a.z += b.z; a.w += b.w; return a;
}
__device__ __forceinline__ float4 ln4(float4 z, float mu, float inv, float4 g, float4 bb) {
    float4 r;
    r.x = fmaf((z.x - mu) * inv, g.x, bb.x);
    r.y = fmaf((z.y - mu) * inv, g.y, bb.y);
    r.z = fmaf((z.z - mu) * inv, g.z, bb.z);
    r.w = fmaf((z.w - mu) * inv, g.w, bb.w);
    return r;
}
__device__ __forceinline__ float4 shflx4(float4 a, int m) {
    float4 r;
    r.x = __shfl_xor(a.x, m, 64); r.y = __shfl_xor(a.y, m, 64);
    r.z = __shfl_xor(a.z, m, 64); r.w = __shfl_xor(a.w, m, 64);
    return r;
}

// 2-sample quarter FMA: one 4-float4 weight read feeds both samples (8 f4-FMAs)
#define FMAD2(SA, SB) do { \
    float4 w0_ = wr[0], w1_ = wr[1], w2_ = wr[2], w3_ = wr[3]; \
    zA0 = sfma4((SA), w0_, zA0); zA1 = sfma4((SA), w1_, zA1); \
    zA2 = sfma4((SA), w2_, zA2); zA3 = sfma4((SA), w3_, zA3); \
    zB0 = sfma4((SB), w0_, zB0); zB1 = sfma4((SB), w1_, zB1); \
    zB2 = sfma4((SB), w2_, zB2); zB3 = sfma4((SB), w3_, zB3); \
    wr += 16; } while (0)

// ---------------- A[u][e][d] precompute ----------------
__global__ void k_prep(const float* __restrict__ gU, const float* __restrict__ gV,
                       const float* __restrict__ ut, float* __restrict__ A)
{
    int idx = blockIdx.x * 256 + threadIdx.x;
    if (idx >= NUSERS * NE) return;
    int u = idx / NE, e = idx - u * NE;

    const float4* up = (const float4*)(ut + (size_t)u * UDIM);
    float4 u0 = up[0], u1 = up[1], u2 = up[2], u3 = up[3];

    float4 va = make_float4(0.f, 0.f, 0.f, 0.f);
    float4 vb = make_float4(0.f, 0.f, 0.f, 0.f);
    const float4* gv4 = (const float4*)gV;
#define UVSTEP(UD, DD) do { \
        float4 g0 = gv4[(e * UDIM + (DD)) * 2 + 0]; \
        float4 g1 = gv4[(e * UDIM + (DD)) * 2 + 1]; \
        va = sfma4((UD), g0, va); vb = sfma4((UD), g1, vb); } while (0)
    UVSTEP(u0.x, 0);  UVSTEP(u0.y, 1);  UVSTEP(u0.z, 2);  UVSTEP(u0.w, 3);
    UVSTEP(u1.x, 4);  UVSTEP(u1.y, 5);  UVSTEP(u1.z, 6);  UVSTEP(u1.w, 7);
    UVSTEP(u2.x, 8);  UVSTEP(u2.y, 9);  UVSTEP(u2.z, 10); UVSTEP(u2.w, 11);
    UVSTEP(u3.x, 12); UVSTEP(u3.y, 13); UVSTEP(u3.z, 14); UVSTEP(u3.w, 15);
#undef UVSTEP

    const float4* gu4 = (const float4*)gU;
    float* Ao = A + ((size_t)u * NE + e) * EMB;
    for (int d = 0; d < EMB; ++d) {
        float4 q0 = gu4[(e * EMB + d) * 2 + 0];
        float4 q1 = gu4[(e * EMB + d) * 2 + 1];
        float a = 0.0f;
        a = fmaf(q0.x, va.x, a); a = fmaf(q0.y, va.y, a);
        a = fmaf(q0.z, va.z, a); a = fmaf(q0.w, va.w, a);
        a = fmaf(q1.x, vb.x, a); a = fmaf(q1.y, vb.y, a);
        a = fmaf(q1.z, vb.z, a); a = fmaf(q1.w, vb.w, a);
        Ao[d] = a;
    }
}

// ---------------- fc1: quarter-split x 2 samples; x streamed; gelu -> h1 ----------------
__global__ __launch_bounds__(256, 2) void k_fc1(
    const float* __restrict__ x,
    const float* __restrict__ w1, const float* __restrict__ b1,
    float* __restrict__ h1_out)
{
    __shared__ __align__(16) float4 s_w1[IN_F * 16];   // 20 KB [d][k4]
    __shared__ __align__(16) float4 s_b1[16];

    const int tid = threadIdx.x;
    {
        const float4* g1 = (const float4*)w1;
        for (int i = tid; i < IN_F * 16; i += 256) s_w1[i] = g1[i];
        if (tid < 16) s_b1[tid] = ((const float4*)b1)[tid];
    }
    __syncthreads();

    const int q  = tid & 3;
    const int pl = tid >> 2;
    const int bA = blockIdx.x * 128 + 2 * pl;
    const int bB = bA + 1;
    const float4* xpA = (const float4*)(x + (size_t)bA * IN_F);
    const float4* xpB = (const float4*)(x + (size_t)bB * IN_F);

    float4 zA0 = s_b1[q*4+0], zA1 = s_b1[q*4+1], zA2 = s_b1[q*4+2], zA3 = s_b1[q*4+3];
    float4 zB0 = zA0, zB1 = zA1, zB2 = zA2, zB3 = zA3;

#pragma unroll 1
    for (int t = 0; t < 10; ++t) {
        float4 a0 = xpA[2*t+0], a1 = xpA[2*t+1];
        float4 b0 = xpB[2*t+0], b1 = xpB[2*t+1];
        const float4* wr = s_w1 + (8*t) * 16 + q * 4;
        FMAD2(a0.x, b0.x); FMAD2(a0.y, b0.y); FMAD2(a0.z, b0.z); FMAD2(a0.w, b0.w);
        FMAD2(a1.x, b1.x); FMAD2(a1.y, b1.y); FMAD2(a1.z, b1.z); FMAD2(a1.w, b1.w);
    }
    zA0 = gelu4(zA0); zA1 = gelu4(zA1); zA2 = gelu4(zA2); zA3 = gelu4(zA3);
    zB0 = gelu4(zB0); zB1 = gelu4(zB1); zB2 = gelu4(zB2); zB3 = gelu4(zB3);

    float4* hoA = (float4*)(h1_out + (size_t)bA * EMB);
    float4* hoB = (float4*)(h1_out + (size_t)bB * EMB);
    hoA[q*4+0] = zA0; hoA[q*4+1] = zA1; hoA[q*4+2] = zA2; hoA[q*4+3] = zA3;
    hoB[q*4+0] = zB0; hoB[q*4+1] = zB1; hoB[q*4+2] = zB2; hoB[q*4+3] = zB3;
}

// ---------------- fc2 + gelu + LN + gate + top2; quarter-split x 2 samples ----------------
__global__ __launch_bounds__(256, 2) void k_fc2gate(
    float* h,                                 // in: h1, out: h (group-owned rows)
    const int* __restrict__ uid,
    const float* __restrict__ w2, const float* __restrict__ b2,
    const float* __restrict__ gam, const float* __restrict__ bet,
    const float* __restrict__ A, const float* __restrict__ gb,
    int* __restrict__ top_e, float* __restrict__ top_w, int* __restrict__ hist)
{
    __shared__ __align__(16) float4 s_w2[EMB * 16];    // 16 KB [d][k4]
    __shared__ __align__(16) float4 s_b2[16], s_ga[16], s_be[16];
    __shared__ float s_gb[NE];
    __shared__ int s_hist[NE];

    const int tid = threadIdx.x;
    {
        const float4* g2 = (const float4*)w2;
        for (int i = tid; i < EMB * 16; i += 256) s_w2[i] = g2[i];
        if (tid < 16) {
            s_b2[tid] = ((const float4*)b2)[tid];
            s_ga[tid] = ((const float4*)gam)[tid];
            s_be[tid] = ((const float4*)bet)[tid];
        }
        if (tid < NE) { s_gb[tid] = gb[tid]; s_hist[tid] = 0; }
    }
    __syncthreads();

    const int q  = tid & 3;
    const int pl = tid >> 2;
    const int bA = blockIdx.x * 128 + 2 * pl;
    const int bB = bA + 1;
    float4* hpA = (float4*)(h + (size_t)bA * EMB);
    float4* hpB = (float4*)(h + (size_t)bB * EMB);

    float4 zA0 = s_b2[q*4+0], zA1 = s_b2[q*4+1], zA2 = s_b2[q*4+2], zA3 = s_b2[q*4+3];
    float4 zB0 = zA0, zB1 = zA1, zB2 = zA2, zB3 = zA3;

#pragma unroll 1
    for (int t = 0; t < 8; ++t) {
        float4 a0 = hpA[2*t+0], a1 = hpA[2*t+1];
        float4 b0 = hpB[2*t+0], b1 = hpB[2*t+1];
        const float4* wr = s_w2 + (8*t) * 16 + q * 4;
        FMAD2(a0.x, b0.x); FMAD2(a0.y, b0.y); FMAD2(a0.z, b0.z); FMAD2(a0.w, b0.w);
        FMAD2(a1.x, b1.x); FMAD2(a1.y, b1.y); FMAD2(a1.z, b1.z); FMAD2(a1.w, b1.w);
    }
    zA0 = gelu4(zA0); zA1 = gelu4(zA1); zA2 = gelu4(zA2); zA3 = gelu4(zA3);
    zB0 = gelu4(zB0); zB1 = gelu4(zB1); zB2 = gelu4(zB2); zB3 = gelu4(zB3);

    // LayerNorm (group butterfly, masks 1/2 stay in 4-lane group)
    float4 sA4 = add4(add4(zA0, zA1), add4(zA2, zA3));
    float slA = (sA4.x + sA4.y) + (sA4.z + sA4.w);
    slA += __shfl_xor(slA, 1, 64); slA += __shfl_xor(slA, 2, 64);
    float muA = slA * (1.0f / 64.0f);
    float4 sB4 = add4(add4(zB0, zB1), add4(zB2, zB3));
    float slB = (sB4.x + sB4.y) + (sB4.z + sB4.w);
    slB += __shfl_xor(slB, 1, 64); slB += __shfl_xor(slB, 2, 64);
    float muB = slB * (1.0f / 64.0f);

    float4 vvA = make_float4(0.f, 0.f, 0.f, 0.f);
    float4 vvB = make_float4(0.f, 0.f, 0.f, 0.f);
#define VACC(V, Z, MU) do { float4 d4; d4.x = (Z).x - (MU); d4.y = (Z).y - (MU); \
        d4.z = (Z).z - (MU); d4.w = (Z).w - (MU); V = ffma4(d4, d4, V); } while (0)
    VACC(vvA, zA0, muA); VACC(vvA, zA1, muA); VACC(vvA, zA2, muA); VACC(vvA, zA3, muA);
    VACC(vvB, zB0, muB); VACC(vvB, zB1, muB); VACC(vvB, zB2, muB); VACC(vvB, zB3, muB);
#undef VACC
    float vlA = (vvA.x + vvA.y) + (vvA.z + vvA.w);
    vlA += __shfl_xor(vlA, 1, 64); vlA += __shfl_xor(vlA, 2, 64);
    float invA = 1.0f / sqrtf(vlA * (1.0f / 64.0f) + 1e-5f);
    float vlB = (vvB.x + vvB.y) + (vvB.z + vvB.w);
    vlB += __shfl_xor(vlB, 1, 64); vlB += __shfl_xor(vlB, 2, 64);
    float invB = 1.0f / sqrtf(vlB * (1.0f / 64.0f) + 1e-5f);

    zA0 = ln4(zA0, muA, invA, s_ga[q*4+0], s_be[q*4+0]);
    zA1 = ln4(zA1, muA, invA, s_ga[q*4+1], s_be[q*4+1]);
    zA2 = ln4(zA2, muA, invA, s_ga[q*4+2], s_be[q*4+2]);
    zA3 = ln4(zA3, muA, invA, s_ga[q*4+3], s_be[q*4+3]);
    zB0 = ln4(zB0, muB, invB, s_ga[q*4+0], s_be[q*4+0]);
    zB1 = ln4(zB1, muB, invB, s_ga[q*4+1], s_be[q*4+1]);
    zB2 = ln4(zB2, muB, invB, s_ga[q*4+2], s_be[q*4+2]);
    zB3 = ln4(zB3, muB, invB, s_ga[q*4+3], s_be[q*4+3]);

    // overwrite h rows (wave-lockstep: all reads precede these writes)
    hpA[q*4+0] = zA0; hpA[q*4+1] = zA1; hpA[q*4+2] = zA2; hpA[q*4+3] = zA3;
    hpB[q*4+0] = zB0; hpB[q*4+1] = zB1; hpB[q*4+2] = zB2; hpB[q*4+3] = zB3;

    // gate: per-e quarter dot + butterfly allreduce; all lanes hold full g
    const int uA = uid[bA], uB = uid[bB];
    const float* AbA = A + (size_t)uA * NE * EMB + q * 16;
    const float* AbB = A + (size_t)uB * NE * EMB + q * 16;
    float gA0,gA1,gA2,gA3,gA4,gA5,gA6,gA7,gA8,gA9,gAa,gAb,gAc,gAd,gAe,gAf;
    float gB0,gB1,gB2,gB3,gB4,gB5,gB6,gB7,gB8,gB9,gBa,gBb,gBc,gBd,gBe,gBf;
#define GDOT(GV, AB, E, Z0, Z1, Z2, Z3) do { \
    const float4* ap = (const float4*)((AB) + (E) * EMB); \
    float4 ac = make_float4(0.f, 0.f, 0.f, 0.f); \
    ac = ffma4(Z0, ap[0], ac); ac = ffma4(Z1, ap[1], ac); \
    ac = ffma4(Z2, ap[2], ac); ac = ffma4(Z3, ap[3], ac); \
    GV = (ac.x + ac.y) + (ac.z + ac.w); \
    GV += __shfl_xor(GV, 1, 64); GV += __shfl_xor(GV, 2, 64); \
    GV += s_gb[(E)]; } while (0)
    GDOT(gA0, AbA, 0,  zA0,zA1,zA2,zA3); GDOT(gA1, AbA, 1,  zA0,zA1,zA2,zA3);
    GDOT(gA2, AbA, 2,  zA0,zA1,zA2,zA3); GDOT(gA3, AbA, 3,  zA0,zA1,zA2,zA3);
    GDOT(gA4, AbA, 4,  zA0,zA1,zA2,zA3); GDOT(gA5, AbA, 5,  zA0,zA1,zA2,zA3);
    GDOT(gA6, AbA, 6,  zA0,zA1,zA2,zA3); GDOT(gA7, AbA, 7,  zA0,zA1,zA2,zA3);
    GDOT(gA8, AbA, 8,  zA0,zA1,zA2,zA3); GDOT(gA9, AbA, 9,  zA0,zA1,zA2,zA3);
    GDOT(gAa, AbA, 10, zA0,zA1,zA2,zA3); GDOT(gAb, AbA, 11, zA0,zA1,zA2,zA3);
    GDOT(gAc, AbA, 12, zA0,zA1,zA2,zA3); GDOT(gAd, AbA, 13, zA0,zA1,zA2,zA3);
    GDOT(gAe, AbA, 14, zA0,zA1,zA2,zA3); GDOT(gAf, AbA, 15, zA0,zA1,zA2,zA3);
    GDOT(gB0, AbB, 0,  zB0,zB1,zB2,zB3); GDOT(gB1, AbB, 1,  zB0,zB1,zB2,zB3);
    GDOT(gB2, AbB, 2,  zB0,zB1,zB2,zB3); GDOT(gB3, AbB, 3,  zB0,zB1,zB2,zB3);
    GDOT(gB4, AbB, 4,  zB0,zB1,zB2,zB3); GDOT(gB5, AbB, 5,  zB0,zB1,zB2,zB3);
    GDOT(gB6, AbB, 6,  zB0,zB1,zB2,zB3); GDOT(gB7, AbB, 7,  zB0,zB1,zB2,zB3);
    GDOT(gB8, AbB, 8,  zB0,zB1,zB2,zB3); GDOT(gB9, AbB, 9,  zB0,zB1,zB2,zB3);
    GDOT(gBa, AbB, 10, zB0,zB1,zB2,zB3); GDOT(gBb, AbB, 11, zB0,zB1,zB2,zB3);
    GDOT(gBc, AbB, 12, zB0,zB1,zB2,zB3); GDOT(gBd, AbB, 13, zB0,zB1,zB2,zB3);
    GDOT(gBe, AbB, 14, zB0,zB1,zB2,zB3); GDOT(gBf, AbB, 15, zB0,zB1,zB2,zB3);
#undef GDOT

#define T2(G, E) do { float gv_ = (G); \
    if (gv_ > m0) { m1 = m0; i1 = i0; m0 = gv_; i0 = (E); } \
    else if (gv_ > m1) { m1 = gv_; i1 = (E); } } while (0)
    if (q == 0) {
        {
            float m0 = -1e30f, m1 = -1e30f; int i0 = 0, i1 = 0;
            T2(gA0,0); T2(gA1,1); T2(gA2,2); T2(gA3,3); T2(gA4,4); T2(gA5,5);
            T2(gA6,6); T2(gA7,7); T2(gA8,8); T2(gA9,9); T2(gAa,10); T2(gAb,11);
            T2(gAc,12); T2(gAd,13); T2(gAe,14); T2(gAf,15);
            float t = expf(m1 - m0);
            top_e[2*bA+0] = i0; top_w[2*bA+0] = 1.0f / (1.0f + t);
            top_e[2*bA+1] = i1; top_w[2*bA+1] = t / (1.0f + t);
            atomicAdd(&s_hist[i0], 1); atomicAdd(&s_hist[i1], 1);
        }
        {
            float m0 = -1e30f, m1 = -1e30f; int i0 = 0, i1 = 0;
            T2(gB0,0); T2(gB1,1); T2(gB2,2); T2(gB3,3); T2(gB4,4); T2(gB5,5);
            T2(gB6,6); T2(gB7,7); T2(gB8,8); T2(gB9,9); T2(gBa,10); T2(gBb,11);
            T2(gBc,12); T2(gBd,13); T2(gBe,14); T2(gBf,15);
            float t = expf(m1 - m0);
            top_e[2*bB+0] = i0; top_w[2*bB+0] = 1.0f / (1.0f + t);
            top_e[2*bB+1] = i1; top_w[2*bB+1] = t / (1.0f + t);
            atomicAdd(&s_hist[i0], 1); atomicAdd(&s_hist[i1], 1);
        }
    }
#undef T2
    __syncthreads();
    if (tid < NE) atomicAdd(&hist[tid], s_hist[tid]);
}

// ---------------- tiny exclusive scan ----------------
__global__ void k_scan(const int* __restrict__ hist, int* __restrict__ offs, int* __restrict__ cur)
{
    if (blockIdx.x == 0 && threadIdx.x == 0) {
        int acc = 0;
        for (int e = 0; e < NE; ++e) { offs[e] = acc; cur[e] = acc; acc += hist[e]; }
    }
}

// ---------------- block-aggregated scatter ----------------
__global__ __launch_bounds__(256) void k_scatter(
    const int* __restrict__ top_e, const float* __restrict__ top_w,
    int* __restrict__ cur, int* __restrict__ pair_b, float* __restrict__ pair_w)
{
    __shared__ int lh[NE];
    __shared__ int lbase[NE];
    const int tid = threadIdx.x;
    if (tid < NE) lh[tid] = 0;
    __syncthreads();

    const int b = blockIdx.x * 256 + tid;
    const int e0 = top_e[2*b+0];
    const int e1 = top_e[2*b+1];
    atomicAdd(&lh[e0], 1);
    atomicAdd(&lh[e1], 1);
    __syncthreads();
    if (tid < NE) {
        lbase[tid] = atomicAdd(&cur[tid], lh[tid]);
        lh[tid] = 0;
    }
    __syncthreads();
    int r0 = atomicAdd(&lh[e0], 1);
    int p0 = lbase[e0] + r0;
    pair_b[p0] = b; pair_w[p0] = top_w[2*b+0];
    int r1 = atomicAdd(&lh[e1], 1);
    int p1 = lbase[e1] + r1;
    pair_b[p1] = b; pair_w[p1] = top_w[2*b+1];
}

// ---------------- expert: quarter-split x 2 pairs per 4-lane group ----------------
#define EXP_BX 128
__global__ __launch_bounds__(256, 2) void k_expert(
    const float* __restrict__ h,
    const int* __restrict__ pair_b, const float* __restrict__ pair_w,
    const int* __restrict__ hist, const int* __restrict__ offs,
    const float* __restrict__ ew1, const float* __restrict__ eb1,
    const float* __restrict__ eg, const float* __restrict__ ebeta,
    const float* __restrict__ ew2, const float* __restrict__ eb2,
    float* __restrict__ out)
{
    const int e = blockIdx.y;
    const int cnt = hist[e];
    if ((int)(blockIdx.x * 128) >= cnt) return;

    __shared__ __align__(16) float4 s_w1[EMB * 16];     // 16 KB [d][k4]
    __shared__ __align__(16) float4 s_w2q[4 * 52];      // per-q k-quarter copies, 208-float stride
    __shared__ __align__(16) float4 s_b1[16], s_ga[16], s_be[16];
    __shared__ float s_b2s[12];

    const int tid = threadIdx.x;
    {
        const float4* g1 = (const float4*)(ew1 + (size_t)e * EMB * EMB);
        for (int i = tid; i < EMB * 16; i += 256) s_w1[i] = g1[i];
        float* w2f = (float*)s_w2q;
        for (int i = tid; i < 4 * 192; i += 256) {
            int cp = i / 192, r = i - cp * 192;
            int k = r / 12, c = r - k * 12;
            // FIX (R12 bug): copy cp holds its OWN k-quarter rows k = cp*16 + k
            w2f[cp * 208 + r] = (c < NCLS)
                ? ew2[((size_t)e * EMB + cp * 16 + k) * NCLS + c] : 0.0f;
        }
        if (tid < 16) {
            s_b1[tid] = ((const float4*)(eb1   + (size_t)e * EMB))[tid];
            s_ga[tid] = ((const float4*)(eg    + (size_t)e * EMB))[tid];
            s_be[tid] = ((const float4*)(ebeta + (size_t)e * EMB))[tid];
        }
        if (tid < 12) s_b2s[tid] = (tid < NCLS) ? eb2[e * NCLS + tid] : 0.0f;
    }
    __syncthreads();

    const int base = offs[e];
    const int q  = tid & 3;
    const int pl = tid >> 2;
    const float4* w2r = s_w2q + q * 52;   // own k-quarter copy (float offset q*208)

    for (int p0 = blockIdx.x * 128; p0 < cnt; p0 += EXP_BX * 128) {
        const int prA = p0 + 2 * pl;
        if (prA >= cnt) continue;
        const int prB = prA + 1;
        const bool vB = (prB < cnt);
        const int idxA = base + prA;
        const int idxB = base + (vB ? prB : prA);
        const int bA = pair_b[idxA], bB = pair_b[idxB];
        const float pwA = pair_w[idxA], pwB = pair_w[idxB];

        const float4* hpA = (const float4*)(h + (size_t)bA * EMB);
        const float4* hpB = (const float4*)(h + (size_t)bB * EMB);

        float4 zA0 = s_b1[q*4+0], zA1 = s_b1[q*4+1], zA2 = s_b1[q*4+2], zA3 = s_b1[q*4+3];
        float4 zB0 = zA0, zB1 = zA1, zB2 = zA2, zB3 = zA3;
#pragma unroll 1
        for (int t = 0; t < 8; ++t) {
            float4 a0 = hpA[2*t+0], a1 = hpA[2*t+1];
            float4 b0 = hpB[2*t+0], b1 = hpB[2*t+1];
            const float4* wr = s_w1 + (8*t) * 16 + q * 4;
            FMAD2(a0.x, b0.x); FMAD2(a0.y, b0.y); FMAD2(a0.z, b0.z); FMAD2(a0.w, b0.w);
            FMAD2(a1.x, b1.x); FMAD2(a1.y, b1.y); FMAD2(a1.z, b1.z); FMAD2(a1.w, b1.w);
        }
        zA0 = gelu4(zA0); zA1 = gelu4(zA1); zA2 = gelu4(zA2); zA3 = gelu4(zA3);
        zB0 = gelu4(zB0); zB1 = gelu4(zB1); zB2 = gelu4(zB2); zB3 = gelu4(zB3);

        // LayerNorm both samples (group butterfly)
        float4 sA4 = add4(add4(zA0, zA1), add4(zA2, zA3));
        float slA = (sA4.x + sA4.y) + (sA4.z + sA4.w);
        slA += __shfl_xor(slA, 1, 64); slA += __shfl_xor(slA, 2, 64);
        float muA = slA * (1.0f / 64.0f);
        float4 sB4 = add4(add4(zB0, zB1), add4(zB2, zB3));
        float slB = (sB4.x + sB4.y) + (sB4.z + sB4.w);
        slB += __shfl_xor(slB, 1, 64); slB += __shfl_xor(slB, 2, 64);
        float muB = slB * (1.0f / 64.0f);

        float4 vvA = make_float4(0.f, 0.f, 0.f, 0.f);
        float4 vvB = make_float4(0.f, 0.f, 0.f, 0.f);
#define VACC(V, Z, MU) do { float4 d4; d4.x = (Z).x - (MU); d4.y = (Z).y - (MU); \
        d4.z = (Z).z - (MU); d4.w = (Z).w - (MU); V = ffma4(d4, d4, V); } while (0)
        VACC(vvA, zA0, muA); VACC(vvA, zA1, muA); VACC(vvA, zA2, muA); VACC(vvA, zA3, muA);
        VACC(vvB, zB0, muB); VACC(vvB, zB1, muB); VACC(vvB, zB2, muB); VACC(vvB, zB3, muB);
#undef VACC
        float vlA = (vvA.x + vvA.y) + (vvA.z + vvA.w);
        vlA += __shfl_xor(vlA, 1, 64); vlA += __shfl_xor(vlA, 2, 64);
        float invA = 1.0f / sqrtf(vlA * (1.0f / 64.0f) + 1e-5f);
        float vlB = (vvB.x + vvB.y) + (vvB.z + vvB.w);
        vlB += __shfl_xor(vlB, 1, 64); vlB += __shfl_xor(vlB, 2, 64);
        float invB = 1.0f / sqrtf(vlB * (1.0f / 64.0f) + 1e-5f);

        zA0 = ln4(zA0, muA, invA, s_ga[q*4+0], s_be[q*4+0]);
        zA1 = ln4(zA1, muA, invA, s_ga[q*4+1], s_be[q*4+1]);
        zA2 = ln4(zA2, muA, invA, s_ga[q*4+2], s_be[q*4+2]);
        zA3 = ln4(zA3, muA, invA, s_ga[q*4+3], s_be[q*4+3]);
        zB0 = ln4(zB0, muB, invB, s_ga[q*4+0], s_be[q*4+0]);
        zB1 = ln4(zB1, muB, invB, s_ga[q*4+1], s_be[q*4+1]);
        zB2 = ln4(zB2, muB, invB, s_ga[q*4+2], s_be[q*4+2]);
        zB3 = ln4(zB3, muB, invB, s_ga[q*4+3], s_be[q*4+3]);

        // fc2 partials over own k-quarter, shared weight reads for both samples
        float4 aA0 = make_float4(0.f,0.f,0.f,0.f), aA1 = aA0, aA2 = aA0;
        float4 aB0 = aA0, aB1 = aA0, aB2 = aA0;
#define EXF2D(ZA, ZB, I) do { \
        const float4* wr2 = w2r + (I) * 3; \
        float4 w0_ = wr2[0], w1_ = wr2[1], w2_ = wr2[2]; \
        aA0 = sfma4((ZA), w0_, aA0); aA1 = sfma4((ZA), w1_, aA1); aA2 = sfma4((ZA), w2_, aA2); \
        aB0 = sfma4((ZB), w0_, aB0); aB1 = sfma4((ZB), w1_, aB1); aB2 = sfma4((ZB), w2_, aB2); } while (0)
        EXF2D(zA0.x, zB0.x, 0);  EXF2D(zA0.y, zB0.y, 1);  EXF2D(zA0.z, zB0.z, 2);  EXF2D(zA0.w, zB0.w, 3);
        EXF2D(zA1.x, zB1.x, 4);  EXF2D(zA1.y, zB1.y, 5);  EXF2D(zA1.z, zB1.z, 6);  EXF2D(zA1.w, zB1.w, 7);
        EXF2D(zA2.x, zB2.x, 8);  EXF2D(zA2.y, zB2.y, 9);  EXF2D(zA2.z, zB2.z, 10); EXF2D(zA2.w, zB2.w, 11);
        EXF2D(zA3.x, zB3.x, 12); EXF2D(zA3.y, zB3.y, 13); EXF2D(zA3.z, zB3.z, 14); EXF2D(zA3.w, zB3.w, 15);
#undef EXF2D

        // combine quarters (butterfly allreduce within group)
        aA0 = add4(aA0, shflx4(aA0, 1)); aA0 = add4(aA0, shflx4(aA0, 2));
        aA1 = add4(aA1, shflx4(aA1, 1)); aA1 = add4(aA1, shflx4(aA1, 2));
        aA2 = add4(aA2, shflx4(aA2, 1)); aA2 = add4(aA2, shflx4(aA2, 2));
        aB0 = add4(aB0, shflx4(aB0, 1)); aB0 = add4(aB0, shflx4(aB0, 2));
        aB1 = add4(aB1, shflx4(aB1, 1)); aB1 = add4(aB1, shflx4(aB1, 2));
        aB2 = add4(aB2, shflx4(aB2, 1)); aB2 = add4(aB2, shflx4(aB2, 2));

        if (q == 0) {
            float* obA = out + (size_t)bA * NCLS;
            atomicAdd(obA + 0, pwA * (aA0.x + s_b2s[0]));
            atomicAdd(obA + 1, pwA * (aA0.y + s_b2s[1]));
            atomicAdd(obA + 2, pwA * (aA0.z + s_b2s[2]));
            atomicAdd(obA + 3, pwA * (aA0.w + s_b2s[3]));
            atomicAdd(obA + 4, pwA * (aA1.x + s_b2s[4]));
            atomicAdd(obA + 5, pwA * (aA1.y + s_b2s[5]));
            atomicAdd(obA + 6, pwA * (aA1.z + s_b2s[6]));
            atomicAdd(obA + 7, pwA * (aA1.w + s_b2s[7]));
            atomicAdd(obA + 8, pwA * (aA2.x + s_b2s[8]));
            atomicAdd(obA + 9, pwA * (aA2.y + s_b2s[9]));
            if (vB) {
                float* obB = out + (size_t)bB * NCLS;
                atomicAdd(obB + 0, pwB * (aB0.x + s_b2s[0]));
                atomicAdd(obB + 1, pwB * (aB0.y + s_b2s[1]));
                atomicAdd(obB + 2, pwB * (aB0.z + s_b2s[2]));
                atomicAdd(obB + 3, pwB * (aB0.w + s_b2s[3]));
                atomicAdd(obB + 4, pwB * (aB1.x + s_b2s[4]));
                atomicAdd(obB + 5, pwB * (aB1.y + s_b2s[5]));
                atomicAdd(obB + 6, pwB * (aB1.z + s_b2s[6]));
                atomicAdd(obB + 7, pwB * (aB1.w + s_b2s[7]));
                atomicAdd(obB + 8, pwB * (aB2.x + s_b2s[8]));
                atomicAdd(obB + 9, pwB * (aB2.y + s_b2s[9]));
            }
        }
    }
}

extern "C" void kernel_launch(void* const* d_in, const int* in_sizes, int n_in,
                              void* d_out, int out_size, void* d_ws, size_t ws_size,
                              hipStream_t stream)
{
    (void)in_sizes; (void)n_in; (void)out_size; (void)ws_size;

    const float* x     = (const float*)d_in[0];
    const int*   uid   = (const int*)  d_in[1];
    const float* bb_w1 = (const float*)d_in[2];
    const float* bb_b1 = (const float*)d_in[3];
    const float* bb_w2 = (const float*)d_in[4];
    const float* bb_b2 = (const float*)d_in[5];
    const float* bb_g  = (const float*)d_in[6];
    const float* bb_be = (const float*)d_in[7];
    const float* gU    = (const float*)d_in[8];
    const float* gV    = (const float*)d_in[9];
    const float* gb    = (const float*)d_in[10];
    const float* e_w1  = (const float*)d_in[11];
    const float* e_b1  = (const float*)d_in[12];
    const float* e_g   = (const float*)d_in[13];
    const float* e_be  = (const float*)d_in[14];
    const float* e_w2  = (const float*)d_in[15];
    const float* e_b2  = (const float*)d_in[16];
    const float* ut    = (const float*)d_in[17];

    float* out = (float*)d_out;
    char*  ws  = (char*)d_ws;

    float* h      = (float*)(ws + OFF_H);
    float* A      = (float*)(ws + OFF_A);
    int*   top_e  = (int*)  (ws + OFF_TOPE);
    float* top_w  = (float*)(ws + OFF_TOPW);
    int*   pair_b = (int*)  (ws + OFF_PAIRB);
    float* pair_w = (float*)(ws + OFF_PAIRW);
    int*   hist   = (int*)  (ws + OFF_HIST);
    int*   offs   = (int*)  (ws + OFF_OFFS);
    int*   cur    = (int*)  (ws + OFF_CUR);

    hipMemsetAsync(out, 0, (size_t)BATCH * NCLS * sizeof(float), stream);
    hipMemsetAsync(hist, 0, NE * sizeof(int), stream);

    k_prep<<<(NUSERS * NE + 255) / 256, 256, 0, stream>>>(gU, gV, ut, A);
    k_fc1<<<BATCH / 128, 256, 0, stream>>>(x, bb_w1, bb_b1, h);
    k_fc2gate<<<BATCH / 128, 256, 0, stream>>>(h, uid, bb_w2, bb_b2, bb_g, bb_be,
                                               A, gb, top_e, top_w, hist);
    k_scan<<<1, 64, 0, stream>>>(hist, offs, cur);
    k_scatter<<<BATCH / 256, 256, 0, stream>>>(top_e, top_w, cur, pair_b, pair_w);
    dim3 eg(EXP_BX, NE);
    k_expert<<<eg, 256, 0, stream>>>(h, pair_b, pair_w, hist, offs,
                                     e_w1, e_b1, e_g, e_be, e_w2, e_b2, out);
}